// Round 1
// baseline (1586.615 us; speedup 1.0000x reference)
//
#include <hip/hip_runtime.h>
#include <math.h>

// GPT forward: V=50257, B=16, T=256, D=64, H=4, HS=16, L=4, F=256
constexpr int NV  = 50257;
constexpr int NB  = 16;
constexpr int NT  = 256;
constexpr int ND  = 64;
constexpr int NH  = 4;
constexpr int NHS = 16;
constexpr int NL  = 4;
constexpr int NF  = 256;
constexpr int NN  = NB * NT;        // 4096 rows
constexpr float EPS = 1e-5f;

constexpr int BNH = 128;            // head tile cols
constexpr int BMH = 128;            // head tile rows
constexpr int NCB = (NV + BNH - 1) / BNH;   // 393 col blocks
constexpr int LOGITS = NN * NV;     // 205,852,672  (fits in int31)

// workspace layout (float offsets)
constexpr int X_OFF  = 0;                       // [NN*ND]
constexpr int Q_OFF  = X_OFF + NN * ND;         // [NN*ND] as [b,h,t,s]
constexpr int K_OFF  = Q_OFF + NN * ND;
constexpr int V_OFF  = K_OFF + NN * ND;
constexpr int O_OFF  = V_OFF + NN * ND;         // [NN*ND] as [n][h*16+s]
constexpr int A_OFF  = O_OFF + NN * ND;         // [NN*NF]
constexpr int XF_OFF = A_OFF + NN * NF;         // [NN*ND]
constexpr int WM_OFF = XF_OFF + NN * ND;        // [NCB*NN]
constexpr int WS_OFF = WM_OFF + NCB * NN;       // [NCB*NN]
constexpr int LP_OFF = WS_OFF + NCB * NN;       // [NN]

// ---------------- embed ----------------
__global__ void k_embed(const int* __restrict__ idx, const float* __restrict__ tok,
                        const float* __restrict__ pos, float* __restrict__ x) {
    int i = blockIdx.x * blockDim.x + threadIdx.x;
    if (i >= NN * ND) return;
    int n = i >> 6, d = i & 63;
    int t = n & (NT - 1);
    x[i] = tok[idx[n] * ND + d] + pos[t * ND + d];
}

// ---------------- layernorm into LDS (64 rows per block, 256 threads) ----------------
__device__ inline void ln_block(float (*hs)[65], const float* __restrict__ x, int r0,
                                const float* __restrict__ g, const float* __restrict__ b, int t) {
    for (int i = t; i < 64 * 64; i += 256)
        hs[i >> 6][i & 63] = x[r0 * ND + i];
    __syncthreads();
    int row = t >> 2, sub = t & 3;
    float s = 0.f, s2 = 0.f;
    for (int j = 0; j < 16; j++) {
        float v = hs[row][sub * 16 + j];
        s += v; s2 += v * v;
    }
    s  += __shfl_xor(s, 1);  s  += __shfl_xor(s, 2);
    s2 += __shfl_xor(s2, 1); s2 += __shfl_xor(s2, 2);
    float mu = s * (1.f / 64.f);
    float var = s2 * (1.f / 64.f) - mu * mu;
    float rs = rsqrtf(var + EPS);
    for (int j = 0; j < 16; j++) {
        int d = sub * 16 + j;
        hs[row][d] = (hs[row][d] - mu) * rs * g[d] + b[d];
    }
    __syncthreads();
}

// ---------------- LN1 + QKV ----------------
__global__ __launch_bounds__(256) void k_ln_qkv(
        const float* __restrict__ x, const float* __restrict__ g, const float* __restrict__ bb,
        const float* __restrict__ Wq, const float* __restrict__ Wk, const float* __restrict__ Wv,
        float* __restrict__ q, float* __restrict__ k, float* __restrict__ v) {
    __shared__ float hs[64][65];
    int t = threadIdx.x;
    int r0 = blockIdx.x * 64;
    ln_block(hs, x, r0, g, bb, t);

    int c = t & 63;            // output column (head*16 + s)
    int rg = t >> 6;           // wave index: 16-row group
    int head = c >> 4, sidx = c & 15;
    float aq[16], ak[16], av[16];
    for (int i = 0; i < 16; i++) { aq[i] = 0.f; ak[i] = 0.f; av[i] = 0.f; }
    for (int kk = 0; kk < 64; kk++) {
        float wq = Wq[(head * 64 + kk) * 16 + sidx];
        float wk = Wk[(head * 64 + kk) * 16 + sidx];
        float wv = Wv[(head * 64 + kk) * 16 + sidx];
        for (int i = 0; i < 16; i++) {
            float h = hs[rg * 16 + i][kk];
            aq[i] += h * wq; ak[i] += h * wk; av[i] += h * wv;
        }
    }
    for (int i = 0; i < 16; i++) {
        int n = r0 + rg * 16 + i;
        int b = n >> 8, tt = n & 255;
        int oidx = ((b * NH + head) * NT + tt) * NHS + sidx;
        q[oidx] = aq[i]; k[oidx] = ak[i]; v[oidx] = av[i];
    }
}

// ---------------- fused causal attention, one block per (b,h) ----------------
__global__ __launch_bounds__(256) void k_attn(
        const float* __restrict__ q, const float* __restrict__ k,
        const float* __restrict__ v, float* __restrict__ o) {
    __shared__ float ks[256][16];
    __shared__ float vs[256][16];
    int bh = blockIdx.x;
    int t = threadIdx.x;   // query row
    const float* kb = k + bh * NT * NHS;
    const float* vb = v + bh * NT * NHS;
    for (int i = t; i < NT * NHS; i += 256) {
        (&ks[0][0])[i] = kb[i];
        (&vs[0][0])[i] = vb[i];
    }
    __syncthreads();
    float qr[16];
    const float* qp = q + bh * NT * NHS + t * NHS;
    for (int j = 0; j < 16; j++) qr[j] = qp[j];
    float m = -1e30f, l = 0.f, acc[16];
    for (int j = 0; j < 16; j++) acc[j] = 0.f;
    for (int u = 0; u <= t; u++) {
        float s = 0.f;
        for (int j = 0; j < 16; j++) s += qr[j] * ks[u][j];
        float mn = fmaxf(m, s);
        float corr = __expf(m - mn);
        float p = __expf(s - mn);
        l = l * corr + p;
        for (int j = 0; j < 16; j++) acc[j] = acc[j] * corr + p * vs[u][j];
        m = mn;
    }
    float inv = 1.f / l;
    int b = bh >> 2, h = bh & 3;
    float* op = o + (b * NT + t) * ND + h * NHS;
    for (int j = 0; j < 16; j++) op[j] = acc[j] * inv;
}

// ---------------- x += o @ Wo + bo ----------------
__global__ __launch_bounds__(256) void k_proj_res(
        const float* __restrict__ o, const float* __restrict__ Wo,
        const float* __restrict__ bo, float* __restrict__ x) {
    __shared__ float os[64][65];
    int t = threadIdx.x;
    int r0 = blockIdx.x * 64;
    for (int i = t; i < 64 * 64; i += 256)
        os[i >> 6][i & 63] = o[r0 * ND + i];
    __syncthreads();
    int c = t & 63, rg = t >> 6;
    float acc[16];
    for (int i = 0; i < 16; i++) acc[i] = 0.f;
    for (int kk = 0; kk < 64; kk++) {
        float w = Wo[kk * 64 + c];
        for (int i = 0; i < 16; i++) acc[i] += os[rg * 16 + i][kk] * w;
    }
    float bias = bo[c];
    for (int i = 0; i < 16; i++) {
        int n = r0 + rg * 16 + i;
        x[n * ND + c] += acc[i] + bias;
    }
}

// ---------------- LN2 + MLP1 + relu ----------------
__global__ __launch_bounds__(256) void k_ln_mlp1(
        const float* __restrict__ x, const float* __restrict__ g, const float* __restrict__ bb,
        const float* __restrict__ W1, const float* __restrict__ b1, float* __restrict__ a) {
    __shared__ float hs[64][65];
    int t = threadIdx.x;
    int r0 = blockIdx.x * 64;
    ln_block(hs, x, r0, g, bb, t);

    int c = t;                 // 0..255 column in F
    float b1c = b1[c];
    for (int rg = 0; rg < 4; rg++) {
        float acc[16];
        for (int i = 0; i < 16; i++) acc[i] = 0.f;
        for (int kk = 0; kk < 64; kk++) {
            float w = W1[kk * NF + c];
            for (int i = 0; i < 16; i++) acc[i] += hs[rg * 16 + i][kk] * w;
        }
        for (int i = 0; i < 16; i++) {
            int n = r0 + rg * 16 + i;
            a[n * NF + c] = fmaxf(acc[i] + b1c, 0.f);
        }
    }
}

// ---------------- x += a @ W2 + b2 ----------------
__global__ __launch_bounds__(256) void k_mlp2_res(
        const float* __restrict__ a, const float* __restrict__ W2,
        const float* __restrict__ b2, float* __restrict__ x) {
    __shared__ float as[64][257];
    int t = threadIdx.x;
    int r0 = blockIdx.x * 64;
    for (int i = t; i < 64 * 256; i += 256)
        as[i >> 8][i & 255] = a[r0 * NF + i];
    __syncthreads();
    int c = t & 63, rg = t >> 6;
    float acc[16];
    for (int i = 0; i < 16; i++) acc[i] = 0.f;
    for (int kk = 0; kk < 256; kk++) {
        float w = W2[kk * 64 + c];
        for (int i = 0; i < 16; i++) acc[i] += as[rg * 16 + i][kk] * w;
    }
    float bias = b2[c];
    for (int i = 0; i < 16; i++) {
        int n = r0 + rg * 16 + i;
        x[n * ND + c] += acc[i] + bias;
    }
}

// ---------------- final LN ----------------
__global__ __launch_bounds__(256) void k_lnf(
        const float* __restrict__ x, const float* __restrict__ g,
        const float* __restrict__ bb, float* __restrict__ xf) {
    __shared__ float hs[64][65];
    int t = threadIdx.x;
    int r0 = blockIdx.x * 64;
    ln_block(hs, x, r0, g, bb, t);
    for (int i = t; i < 64 * 64; i += 256)
        xf[r0 * ND + i] = hs[i >> 6][i & 63];
}

// ---------------- head GEMM + fused logsumexp partials ----------------
__global__ __launch_bounds__(256) void k_head(
        const float* __restrict__ xf, const float* __restrict__ Wh,
        const float* __restrict__ bh, float* __restrict__ out,
        float* __restrict__ wm, float* __restrict__ wsum) {
    __shared__ float xs[BMH][65];
    __shared__ float wS[64][132];
    int t = threadIdx.x;
    int cb = blockIdx.x, rb = blockIdx.y;
    int c0 = cb * BNH;
    int r0 = rb * BMH;
    for (int i = t; i < BMH * 64; i += 256) {
        int r = i >> 6, d = i & 63;
        xs[r][d] = xf[(r0 + r) * ND + d];
    }
    for (int i = t; i < 64 * BNH; i += 256) {
        int kk = i >> 7, c = i & 127;
        int cg = c0 + c;
        wS[kk][c] = (cg < NV) ? Wh[kk * NV + cg] : 0.f;
    }
    __syncthreads();
    int ty = t >> 4, tx = t & 15;
    float acc[8][8];
    for (int i = 0; i < 8; i++)
        for (int j = 0; j < 8; j++) acc[i][j] = 0.f;
    for (int kk = 0; kk < 64; kk++) {
        float av[8];
        for (int i = 0; i < 8; i++) av[i] = xs[ty * 8 + i][kk];
        float4 b0 = *(const float4*)&wS[kk][tx * 8];
        float4 b1 = *(const float4*)&wS[kk][tx * 8 + 4];
        float bv[8] = {b0.x, b0.y, b0.z, b0.w, b1.x, b1.y, b1.z, b1.w};
        for (int i = 0; i < 8; i++)
            for (int j = 0; j < 8; j++) acc[i][j] += av[i] * bv[j];
    }
    int colb = c0 + tx * 8;
    float bias[8];
    for (int j = 0; j < 8; j++) bias[j] = (colb + j < NV) ? bh[colb + j] : 0.f;
    for (int i = 0; i < 8; i++) {
        int row = r0 + ty * 8 + i;
        float lmax = -1e30f;
        for (int j = 0; j < 8; j++) {
            float vv = (colb + j < NV) ? (acc[i][j] + bias[j]) : -1e30f;
            acc[i][j] = vv;
            lmax = fmaxf(lmax, vv);
        }
        for (int off = 1; off < 16; off <<= 1) lmax = fmaxf(lmax, __shfl_xor(lmax, off));
        float lsum = 0.f;
        for (int j = 0; j < 8; j++) {
            if (colb + j < NV) {
                lsum += __expf(acc[i][j] - lmax);
                out[row * NV + colb + j] = acc[i][j];
            }
        }
        for (int off = 1; off < 16; off <<= 1) lsum += __shfl_xor(lsum, off);
        if (tx == 0) {
            wm[cb * NN + row] = lmax;
            wsum[cb * NN + row] = lsum;
        }
    }
}

// ---------------- loss stage 1: per-row logsumexp + target logit ----------------
__global__ void k_loss1(const float* __restrict__ wm, const float* __restrict__ wsum,
                        const float* __restrict__ out, const int* __restrict__ targets,
                        float* __restrict__ lp) {
    int row = blockIdx.x * blockDim.x + threadIdx.x;
    if (row >= NN) return;
    float M = -1e30f, S = 0.f;
    for (int cb = 0; cb < NCB; cb++) {
        float m = wm[cb * NN + row];
        float s = wsum[cb * NN + row];
        float Mn = fmaxf(M, m);
        S = S * __expf(M - Mn) + s * __expf(m - Mn);
        M = Mn;
    }
    float lse = M + logf(S);
    int tg = targets[row];
    float lt = out[row * NV + tg];
    lp[row] = lt - lse;
}

// ---------------- loss stage 2: deterministic mean ----------------
__global__ void k_loss2(const float* __restrict__ lp, float* __restrict__ out) {
    __shared__ float red[4];
    int t = threadIdx.x;
    float s = 0.f;
    for (int i = t; i < NN; i += 256) s += lp[i];
    for (int off = 1; off < 64; off <<= 1) s += __shfl_xor(s, off);
    if ((t & 63) == 0) red[t >> 6] = s;
    __syncthreads();
    if (t == 0) {
        float tot = red[0] + red[1] + red[2] + red[3];
        out[LOGITS] = -tot / (float)NN;
    }
}

extern "C" void kernel_launch(void* const* d_in, const int* in_sizes, int n_in,
                              void* d_out, int out_size, void* d_ws, size_t ws_size,
                              hipStream_t stream) {
    const int*   idx     = (const int*)d_in[0];
    const int*   targets = (const int*)d_in[1];
    const float* tok     = (const float*)d_in[2];
    const float* pos     = (const float*)d_in[3];
    const float* Wq      = (const float*)d_in[4];
    const float* Wk      = (const float*)d_in[5];
    const float* Wv      = (const float*)d_in[6];
    const float* Wo      = (const float*)d_in[7];
    const float* bo      = (const float*)d_in[8];
    const float* ln1g    = (const float*)d_in[9];
    const float* ln1b    = (const float*)d_in[10];
    const float* ln2g    = (const float*)d_in[11];
    const float* ln2b    = (const float*)d_in[12];
    const float* W1      = (const float*)d_in[13];
    const float* b1      = (const float*)d_in[14];
    const float* W2      = (const float*)d_in[15];
    const float* b2      = (const float*)d_in[16];
    const float* lnfg    = (const float*)d_in[17];
    const float* lnfb    = (const float*)d_in[18];
    const float* Wh      = (const float*)d_in[19];
    const float* bh      = (const float*)d_in[20];

    float* ws = (float*)d_ws;
    float* x  = ws + X_OFF;
    float* q  = ws + Q_OFF;
    float* k  = ws + K_OFF;
    float* v  = ws + V_OFF;
    float* o  = ws + O_OFF;
    float* a  = ws + A_OFF;
    float* xf = ws + XF_OFF;
    float* wm = ws + WM_OFF;
    float* wsm= ws + WS_OFF;
    float* lp = ws + LP_OFF;
    float* out = (float*)d_out;

    k_embed<<<(NN * ND + 255) / 256, 256, 0, stream>>>(idx, tok, pos, x);

    for (int l = 0; l < NL; l++) {
        k_ln_qkv<<<NN / 64, 256, 0, stream>>>(x, ln1g + l * ND, ln1b + l * ND,
                                              Wq + l * NH * ND * NHS, Wk + l * NH * ND * NHS,
                                              Wv + l * NH * ND * NHS, q, k, v);
        k_attn<<<NB * NH, 256, 0, stream>>>(q, k, v, o);
        k_proj_res<<<NN / 64, 256, 0, stream>>>(o, Wo + l * ND * ND, bo + l * ND, x);
        k_ln_mlp1<<<NN / 64, 256, 0, stream>>>(x, ln2g + l * ND, ln2b + l * ND,
                                               W1 + l * ND * NF, b1 + l * NF, a);
        k_mlp2_res<<<NN / 64, 256, 0, stream>>>(a, W2 + l * NF * ND, b2 + l * ND, x);
    }

    k_lnf<<<NN / 64, 256, 0, stream>>>(x, lnfg, lnfb, xf);

    dim3 hgrid(NCB, NN / BMH);
    k_head<<<hgrid, 256, 0, stream>>>(xf, Wh, bh, out, wm, wsm);

    k_loss1<<<NN / 256, 256, 0, stream>>>(wm, wsm, out, targets, lp);
    k_loss2<<<1, 256, 0, stream>>>(lp, out);
}

// Round 3
// 928.033 us; speedup vs baseline: 1.7097x; 1.7097x over previous
//
#include <hip/hip_runtime.h>
#include <hip/hip_bf16.h>
#include <math.h>

// GPT forward: V=50257, B=16, T=256, D=64, H=4, HS=16, L=4, F=256
constexpr int NV  = 50257;
constexpr int NB  = 16;
constexpr int NT  = 256;
constexpr int ND  = 64;
constexpr int NH  = 4;
constexpr int NHS = 16;
constexpr int NL  = 4;
constexpr int NF  = 256;
constexpr int NN  = NB * NT;        // 4096 rows
constexpr float EPS = 1e-5f;

constexpr int NCB2 = 197;                    // head col blocks of 256
constexpr int NVP  = NCB2 * 256;             // 50432 padded vocab
constexpr int LOGITS = NN * NV;              // 205,852,672

// workspace layout (float offsets)
constexpr int X_OFF   = 0;                        // [NN*ND]
constexpr int Q_OFF   = X_OFF  + NN * ND;
constexpr int K_OFF   = Q_OFF  + NN * ND;
constexpr int V_OFF   = K_OFF  + NN * ND;
constexpr int O_OFF   = V_OFF  + NN * ND;
constexpr int A_OFF   = O_OFF  + NN * ND;         // [NN*NF]
constexpr int XFB_OFF = A_OFF  + NN * NF;         // bf16 [NN*ND] -> NN*ND/2 floats
constexpr int WM_OFF  = XFB_OFF + NN * ND / 2;    // [NCB2*NN]
constexpr int WS2_OFF = WM_OFF + NCB2 * NN;       // [NCB2*NN]
constexpr int WHB_OFF = WS2_OFF + NCB2 * NN;      // bf16 [NVP*64] -> NVP*32 floats
constexpr int LP_OFF  = WHB_OFF + NVP * 32;       // [NN]

typedef __bf16 bf16x8 __attribute__((ext_vector_type(8)));
typedef float  f32x4  __attribute__((ext_vector_type(4)));

// ---------------- embed ----------------
__global__ void k_embed(const int* __restrict__ idx, const float* __restrict__ tok,
                        const float* __restrict__ pos, float* __restrict__ x) {
    int i = blockIdx.x * blockDim.x + threadIdx.x;
    if (i >= NN * ND) return;
    int n = i >> 6, d = i & 63;
    int t = n & (NT - 1);
    x[i] = tok[idx[n] * ND + d] + pos[t * ND + d];
}

// ---------------- layernorm into LDS (64 rows per block, 256 threads) ----------------
__device__ inline void ln_block(float (*hs)[65], const float* __restrict__ x, int r0,
                                const float* __restrict__ g, const float* __restrict__ b, int t) {
    for (int i = t; i < 64 * 64; i += 256)
        hs[i >> 6][i & 63] = x[r0 * ND + i];
    __syncthreads();
    int row = t >> 2, sub = t & 3;
    float s = 0.f, s2 = 0.f;
    for (int j = 0; j < 16; j++) {
        float v = hs[row][sub * 16 + j];
        s += v; s2 += v * v;
    }
    s  += __shfl_xor(s, 1);  s  += __shfl_xor(s, 2);
    s2 += __shfl_xor(s2, 1); s2 += __shfl_xor(s2, 2);
    float mu = s * (1.f / 64.f);
    float var = s2 * (1.f / 64.f) - mu * mu;
    float rs = rsqrtf(var + EPS);
    for (int j = 0; j < 16; j++) {
        int d = sub * 16 + j;
        hs[row][d] = (hs[row][d] - mu) * rs * g[d] + b[d];
    }
    __syncthreads();
}

// ---------------- LN1 + QKV ----------------
__global__ __launch_bounds__(256) void k_ln_qkv(
        const float* __restrict__ x, const float* __restrict__ g, const float* __restrict__ bb,
        const float* __restrict__ Wq, const float* __restrict__ Wk, const float* __restrict__ Wv,
        float* __restrict__ q, float* __restrict__ k, float* __restrict__ v) {
    __shared__ float hs[64][65];
    int t = threadIdx.x;
    int r0 = blockIdx.x * 64;
    ln_block(hs, x, r0, g, bb, t);

    int c = t & 63;
    int rg = t >> 6;
    int head = c >> 4, sidx = c & 15;
    float aq[16], ak[16], av[16];
    for (int i = 0; i < 16; i++) { aq[i] = 0.f; ak[i] = 0.f; av[i] = 0.f; }
    for (int kk = 0; kk < 64; kk++) {
        float wq = Wq[(head * 64 + kk) * 16 + sidx];
        float wk = Wk[(head * 64 + kk) * 16 + sidx];
        float wv = Wv[(head * 64 + kk) * 16 + sidx];
        for (int i = 0; i < 16; i++) {
            float h = hs[rg * 16 + i][kk];
            aq[i] += h * wq; ak[i] += h * wk; av[i] += h * wv;
        }
    }
    for (int i = 0; i < 16; i++) {
        int n = r0 + rg * 16 + i;
        int b = n >> 8, tt = n & 255;
        int oidx = ((b * NH + head) * NT + tt) * NHS + sidx;
        q[oidx] = aq[i]; k[oidx] = ak[i]; v[oidx] = av[i];
    }
}

// ---------------- fused causal attention, one block per (b,h) ----------------
__global__ __launch_bounds__(256) void k_attn(
        const float* __restrict__ q, const float* __restrict__ k,
        const float* __restrict__ v, float* __restrict__ o) {
    __shared__ float ks[256][16];
    __shared__ float vs[256][16];
    int bh = blockIdx.x;
    int t = threadIdx.x;
    const float* kb = k + bh * NT * NHS;
    const float* vb = v + bh * NT * NHS;
    for (int i = t; i < NT * NHS; i += 256) {
        (&ks[0][0])[i] = kb[i];
        (&vs[0][0])[i] = vb[i];
    }
    __syncthreads();
    float qr[16];
    const float* qp = q + bh * NT * NHS + t * NHS;
    for (int j = 0; j < 16; j++) qr[j] = qp[j];
    float m = -1e30f, l = 0.f, acc[16];
    for (int j = 0; j < 16; j++) acc[j] = 0.f;
    for (int u = 0; u <= t; u++) {
        float s = 0.f;
        for (int j = 0; j < 16; j++) s += qr[j] * ks[u][j];
        float mn = fmaxf(m, s);
        float corr = __expf(m - mn);
        float p = __expf(s - mn);
        l = l * corr + p;
        for (int j = 0; j < 16; j++) acc[j] = acc[j] * corr + p * vs[u][j];
        m = mn;
    }
    float inv = 1.f / l;
    int b = bh >> 2, h = bh & 3;
    float* op = o + (b * NT + t) * ND + h * NHS;
    for (int j = 0; j < 16; j++) op[j] = acc[j] * inv;
}

// ---------------- x += o @ Wo + bo ----------------
__global__ __launch_bounds__(256) void k_proj_res(
        const float* __restrict__ o, const float* __restrict__ Wo,
        const float* __restrict__ bo, float* __restrict__ x) {
    __shared__ float os[64][65];
    int t = threadIdx.x;
    int r0 = blockIdx.x * 64;
    for (int i = t; i < 64 * 64; i += 256)
        os[i >> 6][i & 63] = o[r0 * ND + i];
    __syncthreads();
    int c = t & 63, rg = t >> 6;
    float acc[16];
    for (int i = 0; i < 16; i++) acc[i] = 0.f;
    for (int kk = 0; kk < 64; kk++) {
        float w = Wo[kk * 64 + c];
        for (int i = 0; i < 16; i++) acc[i] += os[rg * 16 + i][kk] * w;
    }
    float bias = bo[c];
    for (int i = 0; i < 16; i++) {
        int n = r0 + rg * 16 + i;
        x[n * ND + c] += acc[i] + bias;
    }
}

// ---------------- LN2 + MLP1 + relu ----------------
__global__ __launch_bounds__(256) void k_ln_mlp1(
        const float* __restrict__ x, const float* __restrict__ g, const float* __restrict__ bb,
        const float* __restrict__ W1, const float* __restrict__ b1, float* __restrict__ a) {
    __shared__ float hs[64][65];
    int t = threadIdx.x;
    int r0 = blockIdx.x * 64;
    ln_block(hs, x, r0, g, bb, t);

    int c = t;
    float b1c = b1[c];
    for (int rg = 0; rg < 4; rg++) {
        float acc[16];
        for (int i = 0; i < 16; i++) acc[i] = 0.f;
        for (int kk = 0; kk < 64; kk++) {
            float w = W1[kk * NF + c];
            for (int i = 0; i < 16; i++) acc[i] += hs[rg * 16 + i][kk] * w;
        }
        for (int i = 0; i < 16; i++) {
            int n = r0 + rg * 16 + i;
            a[n * NF + c] = fmaxf(acc[i] + b1c, 0.f);
        }
    }
}

// ---------------- x += a @ W2 + b2 ----------------
__global__ __launch_bounds__(256) void k_mlp2_res(
        const float* __restrict__ a, const float* __restrict__ W2,
        const float* __restrict__ b2, float* __restrict__ x) {
    __shared__ float as[64][257];
    int t = threadIdx.x;
    int r0 = blockIdx.x * 64;
    for (int i = t; i < 64 * 256; i += 256)
        as[i >> 8][i & 255] = a[r0 * NF + i];
    __syncthreads();
    int c = t & 63, rg = t >> 6;
    float acc[16];
    for (int i = 0; i < 16; i++) acc[i] = 0.f;
    for (int kk = 0; kk < 256; kk++) {
        float w = W2[kk * 64 + c];
        for (int i = 0; i < 16; i++) acc[i] += as[rg * 16 + i][kk] * w;
    }
    float bias = b2[c];
    for (int i = 0; i < 16; i++) {
        int n = r0 + rg * 16 + i;
        x[n * ND + c] += acc[i] + bias;
    }
}

// ---------------- final LN -> bf16 ----------------
__global__ __launch_bounds__(256) void k_lnf(
        const float* __restrict__ x, const float* __restrict__ g,
        const float* __restrict__ bb, __hip_bfloat16* __restrict__ xfb) {
    __shared__ float hs[64][65];
    int t = threadIdx.x;
    int r0 = blockIdx.x * 64;
    ln_block(hs, x, r0, g, bb, t);
    for (int i = t; i < 64 * 64; i += 256)
        xfb[r0 * ND + i] = __float2bfloat16(hs[i >> 6][i & 63]);
}

// ---------------- Whead [64][NV] f32 -> transposed bf16 [NVP][64] ----------------
__global__ __launch_bounds__(256) void k_convW(
        const float* __restrict__ Wh, __hip_bfloat16* __restrict__ whb) {
    __shared__ float w[64][65];
    int t = threadIdx.x;
    int n0 = blockIdx.x * 64;
    for (int i = t; i < 64 * 64; i += 256) {
        int k = i >> 6, c = i & 63;
        int n = n0 + c;
        w[k][c] = (n < NV) ? Wh[k * NV + n] : 0.f;
    }
    __syncthreads();
    int c = t >> 2, kq = t & 3;
    int n = n0 + c;
    union { __hip_bfloat16 h[16]; uint4 u[2]; } pk;
    #pragma unroll
    for (int j = 0; j < 16; j++)
        pk.h[j] = __float2bfloat16(w[kq * 16 + j][c]);
    uint4* dst = (uint4*)(whb + (size_t)n * 64 + kq * 16);
    dst[0] = pk.u[0];
    dst[1] = pk.u[1];
}

// ---------------- head GEMM (bf16 MFMA) + bias + fused row max/sumexp ----------------
// grid (NCB2, NN/64); block 256 = 4 waves; block tile 64 rows x 256 cols,
// wave w handles cols cb*256 + w*64 .. +63, all 64 rows.
// Epilogue: DIRECT per-lane stores (no LDS staging) — correct by construction.
__global__ __launch_bounds__(256) void k_head(
        const __hip_bfloat16* __restrict__ xfb, const __hip_bfloat16* __restrict__ whb,
        const float* __restrict__ bhead, float* __restrict__ out,
        float* __restrict__ wm, float* __restrict__ wsum) {
    __shared__ float smx[4][64];
    __shared__ float ssm[4][64];

    int t = threadIdx.x;
    int w = t >> 6, l = t & 63;
    int lr = l & 15, lg = l >> 4;
    int cb = blockIdx.x, rb = blockIdx.y;
    int r0 = rb * 64;
    int cw = cb * 256 + w * 64;

    // A fragments: a[m][ks], lane holds A[r0+m*16+lr][ks*32+lg*8 .. +7]
    bf16x8 a[4][2], b[4][2];
    {
        const __hip_bfloat16* ap = xfb + (size_t)(r0 + lr) * 64 + lg * 8;
        #pragma unroll
        for (int m = 0; m < 4; m++)
            #pragma unroll
            for (int ks = 0; ks < 2; ks++)
                a[m][ks] = *reinterpret_cast<const bf16x8*>(ap + m * 16 * 64 + ks * 32);
        const __hip_bfloat16* bp = whb + (size_t)(cw + lr) * 64 + lg * 8;
        #pragma unroll
        for (int n = 0; n < 4; n++)
            #pragma unroll
            for (int ks = 0; ks < 2; ks++)
                b[n][ks] = *reinterpret_cast<const bf16x8*>(bp + n * 16 * 64 + ks * 32);
    }

    f32x4 acc[4][4];
    #pragma unroll
    for (int m = 0; m < 4; m++)
        #pragma unroll
        for (int n = 0; n < 4; n++)
            #pragma unroll
            for (int j = 0; j < 4; j++) acc[m][n][j] = 0.f;

    #pragma unroll
    for (int ks = 0; ks < 2; ks++)
        #pragma unroll
        for (int m = 0; m < 4; m++)
            #pragma unroll
            for (int n = 0; n < 4; n++)
                acc[m][n] = __builtin_amdgcn_mfma_f32_16x16x32_bf16(a[m][ks], b[n][ks], acc[m][n], 0, 0, 0);

    // bias + validity per n-frag (lane col = cw + n*16 + lr)
    float bias[4];
    bool  cok[4];
    #pragma unroll
    for (int n = 0; n < 4; n++) {
        int gc = cw + n * 16 + lr;
        cok[n] = (gc < NV);
        bias[n] = cok[n] ? bhead[gc] : 0.f;
    }

    // epilogue: stats + direct stores. D layout: col = lane&15 (lr), row = 4*lg + reg.
    #pragma unroll
    for (int m = 0; m < 4; m++) {
        #pragma unroll
        for (int i = 0; i < 4; i++) {
            int rl = 4 * lg + i;                 // row within 16-row chunk
            int grow = r0 + m * 16 + rl;
            float vals[4];
            float vmax = -1e30f;
            #pragma unroll
            for (int n = 0; n < 4; n++) {
                float v = acc[m][n][i] + bias[n];
                vals[n] = v;
                if (cok[n]) vmax = fmaxf(vmax, v);
            }
            #pragma unroll
            for (int off = 1; off < 16; off <<= 1) vmax = fmaxf(vmax, __shfl_xor(vmax, off));
            float vs = 0.f;
            #pragma unroll
            for (int n = 0; n < 4; n++)
                if (cok[n]) vs += __expf(vals[n] - vmax);
            #pragma unroll
            for (int off = 1; off < 16; off <<= 1) vs += __shfl_xor(vs, off);
            if (lr == 0) {
                smx[w][m * 16 + rl] = vmax;
                ssm[w][m * 16 + rl] = vs;
            }
            // direct stores, guarded
            #pragma unroll
            for (int n = 0; n < 4; n++) {
                int gc = cw + n * 16 + lr;
                if (gc < NV)
                    out[(size_t)grow * NV + gc] = vals[n];
            }
        }
    }

    __syncthreads();
    // combine the 4 wave-slabs' partial (max,sum) -> one partial per block
    if (t < 64) {
        float M = smx[0][t];
        M = fmaxf(M, smx[1][t]);
        M = fmaxf(M, smx[2][t]);
        M = fmaxf(M, smx[3][t]);
        float S = 0.f;
        #pragma unroll
        for (int ww = 0; ww < 4; ww++)
            S += ssm[ww][t] * __expf(smx[ww][t] - M);
        wm[cb * NN + r0 + t] = M;
        wsum[cb * NN + r0 + t] = S;
    }
}

// ---------------- loss stage 1: per-row logsumexp + target logit ----------------
__global__ void k_loss1(const float* __restrict__ wm, const float* __restrict__ wsum,
                        const float* __restrict__ out, const int* __restrict__ targets,
                        float* __restrict__ lp) {
    int row = blockIdx.x * blockDim.x + threadIdx.x;
    if (row >= NN) return;
    float M = -1e30f, S = 0.f;
    for (int cb = 0; cb < NCB2; cb++) {
        float m = wm[cb * NN + row];
        float s = wsum[cb * NN + row];
        float Mn = fmaxf(M, m);
        S = S * __expf(M - Mn) + s * __expf(m - Mn);
        M = Mn;
    }
    float lse = M + logf(S);
    int tg = targets[row];
    float lt = out[(size_t)row * NV + tg];
    lp[row] = lt - lse;
}

// ---------------- loss stage 2: deterministic mean ----------------
__global__ void k_loss2(const float* __restrict__ lp, float* __restrict__ out) {
    __shared__ float red[4];
    int t = threadIdx.x;
    float s = 0.f;
    for (int i = t; i < NN; i += 256) s += lp[i];
    for (int off = 1; off < 64; off <<= 1) s += __shfl_xor(s, off);
    if ((t & 63) == 0) red[t >> 6] = s;
    __syncthreads();
    if (t == 0) {
        float tot = red[0] + red[1] + red[2] + red[3];
        out[LOGITS] = -tot / (float)NN;
    }
}

extern "C" void kernel_launch(void* const* d_in, const int* in_sizes, int n_in,
                              void* d_out, int out_size, void* d_ws, size_t ws_size,
                              hipStream_t stream) {
    const int*   idx     = (const int*)d_in[0];
    const int*   targets = (const int*)d_in[1];
    const float* tok     = (const float*)d_in[2];
    const float* pos     = (const float*)d_in[3];
    const float* Wq      = (const float*)d_in[4];
    const float* Wk      = (const float*)d_in[5];
    const float* Wv      = (const float*)d_in[6];
    const float* Wo      = (const float*)d_in[7];
    const float* bo      = (const float*)d_in[8];
    const float* ln1g    = (const float*)d_in[9];
    const float* ln1b    = (const float*)d_in[10];
    const float* ln2g    = (const float*)d_in[11];
    const float* ln2b    = (const float*)d_in[12];
    const float* W1      = (const float*)d_in[13];
    const float* b1      = (const float*)d_in[14];
    const float* W2      = (const float*)d_in[15];
    const float* b2      = (const float*)d_in[16];
    const float* lnfg    = (const float*)d_in[17];
    const float* lnfb    = (const float*)d_in[18];
    const float* Wh      = (const float*)d_in[19];
    const float* bhead   = (const float*)d_in[20];

    float* ws = (float*)d_ws;
    float* x  = ws + X_OFF;
    float* q  = ws + Q_OFF;
    float* k  = ws + K_OFF;
    float* v  = ws + V_OFF;
    float* o  = ws + O_OFF;
    float* a  = ws + A_OFF;
    __hip_bfloat16* xfb = (__hip_bfloat16*)(ws + XFB_OFF);
    float* wm  = ws + WM_OFF;
    float* wsm = ws + WS2_OFF;
    __hip_bfloat16* whb = (__hip_bfloat16*)(ws + WHB_OFF);
    float* lp  = ws + LP_OFF;
    float* out = (float*)d_out;

    k_convW<<<NVP / 64, 256, 0, stream>>>(Wh, whb);
    k_embed<<<(NN * ND + 255) / 256, 256, 0, stream>>>(idx, tok, pos, x);

    for (int l = 0; l < NL; l++) {
        k_ln_qkv<<<NN / 64, 256, 0, stream>>>(x, ln1g + l * ND, ln1b + l * ND,
                                              Wq + l * NH * ND * NHS, Wk + l * NH * ND * NHS,
                                              Wv + l * NH * ND * NHS, q, k, v);
        k_attn<<<NB * NH, 256, 0, stream>>>(q, k, v, o);
        k_proj_res<<<NN / 64, 256, 0, stream>>>(o, Wo + l * ND * ND, bo + l * ND, x);
        k_ln_mlp1<<<NN / 64, 256, 0, stream>>>(x, ln2g + l * ND, ln2b + l * ND,
                                               W1 + l * ND * NF, b1 + l * NF, a);
        k_mlp2_res<<<NN / 64, 256, 0, stream>>>(a, W2 + l * NF * ND, b2 + l * ND, x);
    }

    k_lnf<<<NN / 64, 256, 0, stream>>>(x, lnfg, lnfb, xfb);

    dim3 hgrid(NCB2, NN / 64);
    k_head<<<hgrid, 256, 0, stream>>>(xfb, whb, bhead, out, wm, wsm);

    k_loss1<<<NN / 256, 256, 0, stream>>>(wm, wsm, out, targets, lp);
    k_loss2<<<1, 256, 0, stream>>>(lp, out);
}

// Round 4
// 623.081 us; speedup vs baseline: 2.5464x; 1.4894x over previous
//
#include <hip/hip_runtime.h>
#include <hip/hip_bf16.h>
#include <math.h>

// GPT forward: V=50257, B=16, T=256, D=64, H=4, HS=16, L=4, F=256
constexpr int NV  = 50257;
constexpr int NB  = 16;
constexpr int NT  = 256;
constexpr int ND  = 64;
constexpr int NH  = 4;
constexpr int NHS = 16;
constexpr int NL  = 4;
constexpr int NF  = 256;
constexpr int NN  = NB * NT;        // 4096 rows
constexpr float EPS = 1e-5f;

constexpr int NCB2 = 197;                    // head col blocks of 256
constexpr int NVP  = NCB2 * 256;             // 50432 padded vocab
constexpr int LOGITS = NN * NV;              // 205,852,672

// workspace layout (float offsets)
constexpr int X_OFF   = 0;                        // [NN*ND]
constexpr int Q_OFF   = X_OFF  + NN * ND;
constexpr int K_OFF   = Q_OFF  + NN * ND;
constexpr int V_OFF   = K_OFF  + NN * ND;
constexpr int O_OFF   = V_OFF  + NN * ND;
constexpr int A_OFF   = O_OFF  + NN * ND;         // (unused now, keeps layout)
constexpr int XFB_OFF = A_OFF  + NN * NF;         // bf16 [NN*ND] -> NN*ND/2 floats
constexpr int WM_OFF  = XFB_OFF + NN * ND / 2;    // [NCB2*NN]
constexpr int WS2_OFF = WM_OFF + NCB2 * NN;       // [NCB2*NN]
constexpr int WHB_OFF = WS2_OFF + NCB2 * NN;      // bf16 [NVP*64] -> NVP*32 floats
constexpr int LP_OFF  = WHB_OFF + NVP * 32;       // [NN]

typedef __bf16 bf16x8 __attribute__((ext_vector_type(8)));
typedef float  f32x4  __attribute__((ext_vector_type(4)));

// ---------------- embed ----------------
__global__ void k_embed(const int* __restrict__ idx, const float* __restrict__ tok,
                        const float* __restrict__ pos, float* __restrict__ x) {
    int i = blockIdx.x * blockDim.x + threadIdx.x;
    if (i >= NN * ND) return;
    int n = i >> 6, d = i & 63;
    int t = n & (NT - 1);
    x[i] = tok[idx[n] * ND + d] + pos[t * ND + d];
}

// ---------------- LN1 + QKV  (16 rows/block, 256 blocks) ----------------
__global__ __launch_bounds__(256) void k_ln_qkv(
        const float* __restrict__ x, const float* __restrict__ g, const float* __restrict__ bb,
        const float* __restrict__ Wq, const float* __restrict__ Wk, const float* __restrict__ Wv,
        float* __restrict__ q, float* __restrict__ k, float* __restrict__ v) {
    __shared__ float hs[16][65];
    int t = threadIdx.x;
    int r0 = blockIdx.x * 16;
    for (int i = t; i < 16 * 64; i += 256)
        hs[i >> 6][i & 63] = x[r0 * 64 + i];
    __syncthreads();
    {
        int row = t >> 4, sub = t & 15;
        float s = 0.f, s2 = 0.f;
        #pragma unroll
        for (int j = 0; j < 4; j++) { float vv = hs[row][sub * 4 + j]; s += vv; s2 += vv * vv; }
        #pragma unroll
        for (int off = 1; off < 16; off <<= 1) { s += __shfl_xor(s, off); s2 += __shfl_xor(s2, off); }
        float mu = s * (1.f / 64.f);
        float var = s2 * (1.f / 64.f) - mu * mu;
        float rs = rsqrtf(var + EPS);
        #pragma unroll
        for (int j = 0; j < 4; j++) {
            int d = sub * 4 + j;
            hs[row][d] = (hs[row][d] - mu) * rs * g[d] + bb[d];
        }
    }
    __syncthreads();
    int c = t & 63, rg = t >> 6;
    int head = c >> 4, sidx = c & 15;
    float aq[4], ak[4], av[4];
    #pragma unroll
    for (int i = 0; i < 4; i++) { aq[i] = 0.f; ak[i] = 0.f; av[i] = 0.f; }
    for (int kk = 0; kk < 64; kk++) {
        float wq = Wq[(head * 64 + kk) * 16 + sidx];
        float wk = Wk[(head * 64 + kk) * 16 + sidx];
        float wv = Wv[(head * 64 + kk) * 16 + sidx];
        #pragma unroll
        for (int i = 0; i < 4; i++) {
            float h = hs[rg * 4 + i][kk];
            aq[i] += h * wq; ak[i] += h * wk; av[i] += h * wv;
        }
    }
    #pragma unroll
    for (int i = 0; i < 4; i++) {
        int n = r0 + rg * 4 + i;
        int b = n >> 8, tt = n & 255;
        int oidx = ((b * NH + head) * NT + tt) * NHS + sidx;
        q[oidx] = aq[i]; k[oidx] = ak[i]; v[oidx] = av[i];
    }
}

// ---------------- fused causal attention (split-u), 256 blocks ----------------
// block = (bh, tq): 64 query rows; 4 threads per row, u strided by 4.
__global__ __launch_bounds__(256) void k_attn(
        const float* __restrict__ q, const float* __restrict__ k,
        const float* __restrict__ v, float* __restrict__ o) {
    __shared__ float ks[256][16];
    __shared__ float vs[256][16];
    int blk = blockIdx.x;
    int bh = blk >> 2;
    int tq = blk & 3;
    int t = threadIdx.x;
    int tl = t >> 2, sub = t & 3;
    int tt = tq * 64 + tl;
    int nrows = tq * 64 + 64;
    const float* kb = k + bh * NT * NHS;
    const float* vb = v + bh * NT * NHS;
    for (int i = t; i < nrows * 16; i += 256) {
        (&ks[0][0])[i] = kb[i];
        (&vs[0][0])[i] = vb[i];
    }
    __syncthreads();
    float qr[16];
    const float* qp = q + bh * NT * NHS + tt * NHS;
    #pragma unroll
    for (int j = 0; j < 16; j += 4) {
        float4 qv = *(const float4*)(qp + j);
        qr[j] = qv.x; qr[j+1] = qv.y; qr[j+2] = qv.z; qr[j+3] = qv.w;
    }
    float m = -1e30f, l = 0.f, acc[16];
    #pragma unroll
    for (int j = 0; j < 16; j++) acc[j] = 0.f;
    for (int u = sub; u <= tt; u += 4) {
        float s = 0.f;
        #pragma unroll
        for (int j = 0; j < 16; j++) s += qr[j] * ks[u][j];
        float mn = fmaxf(m, s);
        float corr = __expf(m - mn);
        float p = __expf(s - mn);
        l = l * corr + p;
        #pragma unroll
        for (int j = 0; j < 16; j++) acc[j] = acc[j] * corr + p * vs[u][j];
        m = mn;
    }
    // combine 4 sub-partials (lanes differ only in low-2 bits)
    #pragma unroll
    for (int off = 1; off < 4; off <<= 1) {
        float mo = __shfl_xor(m, off);
        float lo = __shfl_xor(l, off);
        float mn = fmaxf(m, mo);
        float c1 = __expf(m - mn), c2 = __expf(mo - mn);
        l = l * c1 + lo * c2;
        #pragma unroll
        for (int j = 0; j < 16; j++) {
            float ao = __shfl_xor(acc[j], off);
            acc[j] = acc[j] * c1 + ao * c2;
        }
        m = mn;
    }
    float inv = 1.f / l;
    int b = bh >> 2, h = bh & 3;
    float* op = o + (b * NT + tt) * ND + h * NHS;
    float o0, o1, o2, o3;
    if (sub == 0)      { o0 = acc[0];  o1 = acc[1];  o2 = acc[2];  o3 = acc[3];  }
    else if (sub == 1) { o0 = acc[4];  o1 = acc[5];  o2 = acc[6];  o3 = acc[7];  }
    else if (sub == 2) { o0 = acc[8];  o1 = acc[9];  o2 = acc[10]; o3 = acc[11]; }
    else               { o0 = acc[12]; o1 = acc[13]; o2 = acc[14]; o3 = acc[15]; }
    float4 ov = make_float4(o0 * inv, o1 * inv, o2 * inv, o3 * inv);
    *(float4*)(op + sub * 4) = ov;
}

// ---------------- fused proj+res+LN2+MLP1+MLP2+res (16 rows/block) ----------------
__global__ __launch_bounds__(256) void k_post(
        const float* __restrict__ o, const float* __restrict__ Wo, const float* __restrict__ bo,
        const float* __restrict__ g2, const float* __restrict__ bg2,
        const float* __restrict__ W1, const float* __restrict__ b1,
        const float* __restrict__ W2, const float* __restrict__ b2m,
        float* __restrict__ x) {
    __shared__ float os[16][65];
    __shared__ float xs[16][65];
    __shared__ float as[16][257];
    int t = threadIdx.x;
    int r0 = blockIdx.x * 16;
    for (int i = t; i < 16 * 64; i += 256)
        os[i >> 6][i & 63] = o[r0 * 64 + i];
    __syncthreads();
    int c = t & 63, rg = t >> 6;
    {
        float pr[4] = {0.f, 0.f, 0.f, 0.f};
        for (int kk = 0; kk < 64; kk++) {
            float w = Wo[kk * 64 + c];
            #pragma unroll
            for (int i = 0; i < 4; i++) pr[i] += os[rg * 4 + i][kk] * w;
        }
        float bias = bo[c];
        #pragma unroll
        for (int i = 0; i < 4; i++) {
            int row = rg * 4 + i;
            xs[row][c] = x[(r0 + row) * 64 + c] + pr[i] + bias;
        }
    }
    __syncthreads();
    {
        int row = t >> 4, sub = t & 15;
        float s = 0.f, s2 = 0.f;
        #pragma unroll
        for (int j = 0; j < 4; j++) { float vv = xs[row][sub * 4 + j]; s += vv; s2 += vv * vv; }
        #pragma unroll
        for (int off = 1; off < 16; off <<= 1) { s += __shfl_xor(s, off); s2 += __shfl_xor(s2, off); }
        float mu = s * (1.f / 64.f);
        float var = s2 * (1.f / 64.f) - mu * mu;
        float rs = rsqrtf(var + EPS);
        #pragma unroll
        for (int j = 0; j < 4; j++) {
            int d = sub * 4 + j;
            os[row][d] = (xs[row][d] - mu) * rs * g2[d] + bg2[d];
        }
    }
    __syncthreads();
    {
        float m1[16];
        #pragma unroll
        for (int i = 0; i < 16; i++) m1[i] = 0.f;
        for (int kk = 0; kk < 64; kk++) {
            float w = W1[kk * NF + t];
            #pragma unroll
            for (int i = 0; i < 16; i++) m1[i] += os[i][kk] * w;
        }
        float bb1 = b1[t];
        #pragma unroll
        for (int i = 0; i < 16; i++) as[i][t] = fmaxf(m1[i] + bb1, 0.f);
    }
    __syncthreads();
    {
        float m2[4] = {0.f, 0.f, 0.f, 0.f};
        for (int kk = 0; kk < 256; kk++) {
            float w = W2[kk * 64 + c];
            #pragma unroll
            for (int i = 0; i < 4; i++) m2[i] += as[rg * 4 + i][kk] * w;
        }
        float bias = b2m[c];
        #pragma unroll
        for (int i = 0; i < 4; i++) {
            int row = rg * 4 + i;
            x[(r0 + row) * 64 + c] = xs[row][c] + m2[i] + bias;
        }
    }
}

// ---------------- final LN -> bf16 (16 rows/block) ----------------
__global__ __launch_bounds__(256) void k_lnf(
        const float* __restrict__ x, const float* __restrict__ g,
        const float* __restrict__ bb, __hip_bfloat16* __restrict__ xfb) {
    __shared__ float hs[16][65];
    int t = threadIdx.x;
    int r0 = blockIdx.x * 16;
    for (int i = t; i < 16 * 64; i += 256)
        hs[i >> 6][i & 63] = x[r0 * 64 + i];
    __syncthreads();
    {
        int row = t >> 4, sub = t & 15;
        float s = 0.f, s2 = 0.f;
        #pragma unroll
        for (int j = 0; j < 4; j++) { float vv = hs[row][sub * 4 + j]; s += vv; s2 += vv * vv; }
        #pragma unroll
        for (int off = 1; off < 16; off <<= 1) { s += __shfl_xor(s, off); s2 += __shfl_xor(s2, off); }
        float mu = s * (1.f / 64.f);
        float var = s2 * (1.f / 64.f) - mu * mu;
        float rs = rsqrtf(var + EPS);
        #pragma unroll
        for (int j = 0; j < 4; j++) {
            int d = sub * 4 + j;
            hs[row][d] = (hs[row][d] - mu) * rs * g[d] + bb[d];
        }
    }
    __syncthreads();
    for (int i = t; i < 16 * 64; i += 256)
        xfb[r0 * 64 + i] = __float2bfloat16(hs[i >> 6][i & 63]);
}

// ---------------- Whead [64][NV] f32 -> transposed bf16 [NVP][64] ----------------
__global__ __launch_bounds__(256) void k_convW(
        const float* __restrict__ Wh, __hip_bfloat16* __restrict__ whb) {
    __shared__ float w[64][65];
    int t = threadIdx.x;
    int n0 = blockIdx.x * 64;
    for (int i = t; i < 64 * 64; i += 256) {
        int k = i >> 6, c = i & 63;
        int n = n0 + c;
        w[k][c] = (n < NV) ? Wh[k * NV + n] : 0.f;
    }
    __syncthreads();
    int c = t >> 2, kq = t & 3;
    int n = n0 + c;
    union { __hip_bfloat16 h[16]; uint4 u[2]; } pk;
    #pragma unroll
    for (int j = 0; j < 16; j++)
        pk.h[j] = __float2bfloat16(w[kq * 16 + j][c]);
    uint4* dst = (uint4*)(whb + (size_t)n * 64 + kq * 16);
    dst[0] = pk.u[0];
    dst[1] = pk.u[1];
}

// ---------------- head GEMM (bf16 MFMA) + bias + fused row max/sumexp ----------------
__global__ __launch_bounds__(256) void k_head(
        const __hip_bfloat16* __restrict__ xfb, const __hip_bfloat16* __restrict__ whb,
        const float* __restrict__ bhead, float* __restrict__ out,
        float* __restrict__ wm, float* __restrict__ wsum) {
    __shared__ float smx[4][64];
    __shared__ float ssm[4][64];

    int t = threadIdx.x;
    int w = t >> 6, l = t & 63;
    int lr = l & 15, lg = l >> 4;
    int cb = blockIdx.x, rb = blockIdx.y;
    int r0 = rb * 64;
    int cw = cb * 256 + w * 64;

    bf16x8 a[4][2], b[4][2];
    {
        const __hip_bfloat16* ap = xfb + (size_t)(r0 + lr) * 64 + lg * 8;
        #pragma unroll
        for (int m = 0; m < 4; m++)
            #pragma unroll
            for (int ks = 0; ks < 2; ks++)
                a[m][ks] = *reinterpret_cast<const bf16x8*>(ap + m * 16 * 64 + ks * 32);
        const __hip_bfloat16* bp = whb + (size_t)(cw + lr) * 64 + lg * 8;
        #pragma unroll
        for (int n = 0; n < 4; n++)
            #pragma unroll
            for (int ks = 0; ks < 2; ks++)
                b[n][ks] = *reinterpret_cast<const bf16x8*>(bp + n * 16 * 64 + ks * 32);
    }

    f32x4 acc[4][4];
    #pragma unroll
    for (int m = 0; m < 4; m++)
        #pragma unroll
        for (int n = 0; n < 4; n++)
            #pragma unroll
            for (int j = 0; j < 4; j++) acc[m][n][j] = 0.f;

    #pragma unroll
    for (int ks = 0; ks < 2; ks++)
        #pragma unroll
        for (int m = 0; m < 4; m++)
            #pragma unroll
            for (int n = 0; n < 4; n++)
                acc[m][n] = __builtin_amdgcn_mfma_f32_16x16x32_bf16(a[m][ks], b[n][ks], acc[m][n], 0, 0, 0);

    float bias[4];
    bool  cok[4];
    #pragma unroll
    for (int n = 0; n < 4; n++) {
        int gc = cw + n * 16 + lr;
        cok[n] = (gc < NV);
        bias[n] = cok[n] ? bhead[gc] : 0.f;
    }

    #pragma unroll
    for (int m = 0; m < 4; m++) {
        #pragma unroll
        for (int i = 0; i < 4; i++) {
            int rl = 4 * lg + i;
            int grow = r0 + m * 16 + rl;
            float vals[4];
            float vmax = -1e30f;
            #pragma unroll
            for (int n = 0; n < 4; n++) {
                float v = acc[m][n][i] + bias[n];
                vals[n] = v;
                if (cok[n]) vmax = fmaxf(vmax, v);
            }
            #pragma unroll
            for (int off = 1; off < 16; off <<= 1) vmax = fmaxf(vmax, __shfl_xor(vmax, off));
            float vs = 0.f;
            #pragma unroll
            for (int n = 0; n < 4; n++)
                if (cok[n]) vs += __expf(vals[n] - vmax);
            #pragma unroll
            for (int off = 1; off < 16; off <<= 1) vs += __shfl_xor(vs, off);
            if (lr == 0) {
                smx[w][m * 16 + rl] = vmax;
                ssm[w][m * 16 + rl] = vs;
            }
            #pragma unroll
            for (int n = 0; n < 4; n++) {
                int gc = cw + n * 16 + lr;
                if (gc < NV)
                    out[(size_t)grow * NV + gc] = vals[n];
            }
        }
    }

    __syncthreads();
    if (t < 64) {
        float M = smx[0][t];
        M = fmaxf(M, smx[1][t]);
        M = fmaxf(M, smx[2][t]);
        M = fmaxf(M, smx[3][t]);
        float S = 0.f;
        #pragma unroll
        for (int ww = 0; ww < 4; ww++)
            S += ssm[ww][t] * __expf(smx[ww][t] - M);
        wm[cb * NN + r0 + t] = M;
        wsum[cb * NN + r0 + t] = S;
    }
}

// ---------------- loss stage 1 ----------------
__global__ void k_loss1(const float* __restrict__ wm, const float* __restrict__ wsum,
                        const float* __restrict__ out, const int* __restrict__ targets,
                        float* __restrict__ lp) {
    int row = blockIdx.x * blockDim.x + threadIdx.x;
    if (row >= NN) return;
    float M = -1e30f, S = 0.f;
    for (int cb = 0; cb < NCB2; cb++) {
        float m = wm[cb * NN + row];
        float s = wsum[cb * NN + row];
        float Mn = fmaxf(M, m);
        S = S * __expf(M - Mn) + s * __expf(m - Mn);
        M = Mn;
    }
    float lse = M + logf(S);
    int tg = targets[row];
    float lt = out[(size_t)row * NV + tg];
    lp[row] = lt - lse;
}

// ---------------- loss stage 2 ----------------
__global__ void k_loss2(const float* __restrict__ lp, float* __restrict__ out) {
    __shared__ float red[4];
    int t = threadIdx.x;
    float s = 0.f;
    for (int i = t; i < NN; i += 256) s += lp[i];
    for (int off = 1; off < 64; off <<= 1) s += __shfl_xor(s, off);
    if ((t & 63) == 0) red[t >> 6] = s;
    __syncthreads();
    if (t == 0) {
        float tot = red[0] + red[1] + red[2] + red[3];
        out[LOGITS] = -tot / (float)NN;
    }
}

extern "C" void kernel_launch(void* const* d_in, const int* in_sizes, int n_in,
                              void* d_out, int out_size, void* d_ws, size_t ws_size,
                              hipStream_t stream) {
    const int*   idx     = (const int*)d_in[0];
    const int*   targets = (const int*)d_in[1];
    const float* tok     = (const float*)d_in[2];
    const float* pos     = (const float*)d_in[3];
    const float* Wq      = (const float*)d_in[4];
    const float* Wk      = (const float*)d_in[5];
    const float* Wv      = (const float*)d_in[6];
    const float* Wo      = (const float*)d_in[7];
    const float* bo      = (const float*)d_in[8];
    const float* ln1g    = (const float*)d_in[9];
    const float* ln1b    = (const float*)d_in[10];
    const float* ln2g    = (const float*)d_in[11];
    const float* ln2b    = (const float*)d_in[12];
    const float* W1      = (const float*)d_in[13];
    const float* b1      = (const float*)d_in[14];
    const float* W2      = (const float*)d_in[15];
    const float* b2      = (const float*)d_in[16];
    const float* lnfg    = (const float*)d_in[17];
    const float* lnfb    = (const float*)d_in[18];
    const float* Wh      = (const float*)d_in[19];
    const float* bhead   = (const float*)d_in[20];

    float* ws = (float*)d_ws;
    float* x  = ws + X_OFF;
    float* q  = ws + Q_OFF;
    float* k  = ws + K_OFF;
    float* v  = ws + V_OFF;
    float* o  = ws + O_OFF;
    __hip_bfloat16* xfb = (__hip_bfloat16*)(ws + XFB_OFF);
    float* wm  = ws + WM_OFF;
    float* wsm = ws + WS2_OFF;
    __hip_bfloat16* whb = (__hip_bfloat16*)(ws + WHB_OFF);
    float* lp  = ws + LP_OFF;
    float* out = (float*)d_out;

    k_convW<<<NVP / 64, 256, 0, stream>>>(Wh, whb);
    k_embed<<<(NN * ND + 255) / 256, 256, 0, stream>>>(idx, tok, pos, x);

    for (int l = 0; l < NL; l++) {
        k_ln_qkv<<<NN / 16, 256, 0, stream>>>(x, ln1g + l * ND, ln1b + l * ND,
                                              Wq + l * NH * ND * NHS, Wk + l * NH * ND * NHS,
                                              Wv + l * NH * ND * NHS, q, k, v);
        k_attn<<<NB * NH * 4, 256, 0, stream>>>(q, k, v, o);
        k_post<<<NN / 16, 256, 0, stream>>>(o, Wo + l * ND * ND, bo + l * ND,
                                            ln2g + l * ND, ln2b + l * ND,
                                            W1 + l * ND * NF, b1 + l * NF,
                                            W2 + l * NF * ND, b2 + l * ND, x);
    }

    k_lnf<<<NN / 16, 256, 0, stream>>>(x, lnfg, lnfb, xfb);

    dim3 hgrid(NCB2, NN / 64);
    k_head<<<hgrid, 256, 0, stream>>>(xfb, whb, bhead, out, wm, wsm);

    k_loss1<<<NN / 256, 256, 0, stream>>>(wm, wsm, out, targets, lp);
    k_loss2<<<1, 256, 0, stream>>>(lp, out);
}

// Round 5
// 589.011 us; speedup vs baseline: 2.6937x; 1.0578x over previous
//
#include <hip/hip_runtime.h>
#include <hip/hip_bf16.h>
#include <math.h>

// GPT forward: V=50257, B=16, T=256, D=64, H=4, HS=16, L=4, F=256
constexpr int NV  = 50257;
constexpr int NB  = 16;
constexpr int NT  = 256;
constexpr int ND  = 64;
constexpr int NH  = 4;
constexpr int NHS = 16;
constexpr int NL  = 4;
constexpr int NF  = 256;
constexpr int NN  = NB * NT;        // 4096 rows
constexpr float EPS = 1e-5f;

constexpr int NCB2 = 197;                    // head col blocks of 256
constexpr int NVP  = NCB2 * 256;             // 50432 padded vocab
constexpr int LOGITS = NN * NV;              // 205,852,672

// workspace layout (float offsets)
constexpr int X_OFF   = 0;                        // [NN*ND]
constexpr int Q_OFF   = X_OFF  + NN * ND;
constexpr int K_OFF   = Q_OFF  + NN * ND;
constexpr int V_OFF   = K_OFF  + NN * ND;
constexpr int O_OFF   = V_OFF  + NN * ND;
constexpr int A_OFF   = O_OFF  + NN * ND;         // (spacer)
constexpr int XFB_OFF = A_OFF  + NN * NF;         // bf16 [NN*ND] -> NN*ND/2 floats
constexpr int WM_OFF  = XFB_OFF + NN * ND / 2;    // (spacer, unused)
constexpr int WS2_OFF = WM_OFF + NCB2 * NN;       // [NCB2*NN] sum-exp partials
constexpr int WHB_OFF = WS2_OFF + NCB2 * NN;      // bf16 [NVP*64] -> NVP*32 floats
constexpr int LP_OFF  = WHB_OFF + NVP * 32;       // [NN]

typedef __bf16 bf16x8 __attribute__((ext_vector_type(8)));
typedef float  f32x4  __attribute__((ext_vector_type(4)));

// ---------------- LN1 + QKV  (16 rows/block, 256 blocks); first: fused embed ----------------
__global__ __launch_bounds__(256) void k_ln_qkv(
        float* __restrict__ x, const float* __restrict__ g, const float* __restrict__ bb,
        const float* __restrict__ Wq, const float* __restrict__ Wk, const float* __restrict__ Wv,
        float* __restrict__ q, float* __restrict__ k, float* __restrict__ v,
        const int* __restrict__ idx, const float* __restrict__ tok,
        const float* __restrict__ pos, int first) {
    __shared__ float hs[16][65];
    int t = threadIdx.x;
    int r0 = blockIdx.x * 16;
    if (first) {
        for (int i = t; i < 16 * 64; i += 256) {
            int n = r0 + (i >> 6);
            int tt = n & (NT - 1), d = i & 63;
            float e = tok[idx[n] * ND + d] + pos[tt * ND + d];
            hs[i >> 6][i & 63] = e;
            x[(size_t)r0 * 64 + i] = e;
        }
    } else {
        for (int i = t; i < 16 * 64; i += 256)
            hs[i >> 6][i & 63] = x[r0 * 64 + i];
    }
    __syncthreads();
    {
        int row = t >> 4, sub = t & 15;
        float s = 0.f, s2 = 0.f;
        #pragma unroll
        for (int j = 0; j < 4; j++) { float vv = hs[row][sub * 4 + j]; s += vv; s2 += vv * vv; }
        #pragma unroll
        for (int off = 1; off < 16; off <<= 1) { s += __shfl_xor(s, off); s2 += __shfl_xor(s2, off); }
        float mu = s * (1.f / 64.f);
        float var = s2 * (1.f / 64.f) - mu * mu;
        float rs = rsqrtf(var + EPS);
        #pragma unroll
        for (int j = 0; j < 4; j++) {
            int d = sub * 4 + j;
            hs[row][d] = (hs[row][d] - mu) * rs * g[d] + bb[d];
        }
    }
    __syncthreads();
    int c = t & 63, rg = t >> 6;
    int head = c >> 4, sidx = c & 15;
    float aq[4], ak[4], av[4];
    #pragma unroll
    for (int i = 0; i < 4; i++) { aq[i] = 0.f; ak[i] = 0.f; av[i] = 0.f; }
    for (int kk = 0; kk < 64; kk++) {
        float wq = Wq[(head * 64 + kk) * 16 + sidx];
        float wk = Wk[(head * 64 + kk) * 16 + sidx];
        float wv = Wv[(head * 64 + kk) * 16 + sidx];
        #pragma unroll
        for (int i = 0; i < 4; i++) {
            float h = hs[rg * 4 + i][kk];
            aq[i] += h * wq; ak[i] += h * wk; av[i] += h * wv;
        }
    }
    #pragma unroll
    for (int i = 0; i < 4; i++) {
        int n = r0 + rg * 4 + i;
        int b = n >> 8, tt = n & 255;
        int oidx = ((b * NH + head) * NT + tt) * NHS + sidx;
        q[oidx] = aq[i]; k[oidx] = ak[i]; v[oidx] = av[i];
    }
}

// ---------------- fused causal attention (split-u), 256 blocks ----------------
__global__ __launch_bounds__(256) void k_attn(
        const float* __restrict__ q, const float* __restrict__ k,
        const float* __restrict__ v, float* __restrict__ o) {
    __shared__ float ks[256][16];
    __shared__ float vs[256][16];
    int blk = blockIdx.x;
    int bh = blk >> 2;
    int tq = blk & 3;
    int t = threadIdx.x;
    int tl = t >> 2, sub = t & 3;
    int tt = tq * 64 + tl;
    int nrows = tq * 64 + 64;
    const float* kb = k + bh * NT * NHS;
    const float* vb = v + bh * NT * NHS;
    for (int i = t; i < nrows * 16; i += 256) {
        (&ks[0][0])[i] = kb[i];
        (&vs[0][0])[i] = vb[i];
    }
    __syncthreads();
    float qr[16];
    const float* qp = q + bh * NT * NHS + tt * NHS;
    #pragma unroll
    for (int j = 0; j < 16; j += 4) {
        float4 qv = *(const float4*)(qp + j);
        qr[j] = qv.x; qr[j+1] = qv.y; qr[j+2] = qv.z; qr[j+3] = qv.w;
    }
    float m = -1e30f, l = 0.f, acc[16];
    #pragma unroll
    for (int j = 0; j < 16; j++) acc[j] = 0.f;
    for (int u = sub; u <= tt; u += 4) {
        float s = 0.f;
        #pragma unroll
        for (int j = 0; j < 16; j++) s += qr[j] * ks[u][j];
        float mn = fmaxf(m, s);
        float corr = __expf(m - mn);
        float p = __expf(s - mn);
        l = l * corr + p;
        #pragma unroll
        for (int j = 0; j < 16; j++) acc[j] = acc[j] * corr + p * vs[u][j];
        m = mn;
    }
    #pragma unroll
    for (int off = 1; off < 4; off <<= 1) {
        float mo = __shfl_xor(m, off);
        float lo = __shfl_xor(l, off);
        float mn = fmaxf(m, mo);
        float c1 = __expf(m - mn), c2 = __expf(mo - mn);
        l = l * c1 + lo * c2;
        #pragma unroll
        for (int j = 0; j < 16; j++) {
            float ao = __shfl_xor(acc[j], off);
            acc[j] = acc[j] * c1 + ao * c2;
        }
        m = mn;
    }
    float inv = 1.f / l;
    int b = bh >> 2, h = bh & 3;
    float* op = o + (b * NT + tt) * ND + h * NHS;
    float o0, o1, o2, o3;
    if (sub == 0)      { o0 = acc[0];  o1 = acc[1];  o2 = acc[2];  o3 = acc[3];  }
    else if (sub == 1) { o0 = acc[4];  o1 = acc[5];  o2 = acc[6];  o3 = acc[7];  }
    else if (sub == 2) { o0 = acc[8];  o1 = acc[9];  o2 = acc[10]; o3 = acc[11]; }
    else               { o0 = acc[12]; o1 = acc[13]; o2 = acc[14]; o3 = acc[15]; }
    float4 ov = make_float4(o0 * inv, o1 * inv, o2 * inv, o3 * inv);
    *(float4*)(op + sub * 4) = ov;
}

// ---------------- fused proj+res+LN2+MLP1+MLP2+res (16 rows/block) ----------------
// last: instead of writing x, apply final LN and write bf16 xfb.
__global__ __launch_bounds__(256) void k_post(
        const float* __restrict__ o, const float* __restrict__ Wo, const float* __restrict__ bo,
        const float* __restrict__ g2, const float* __restrict__ bg2,
        const float* __restrict__ W1, const float* __restrict__ b1,
        const float* __restrict__ W2, const float* __restrict__ b2m,
        float* __restrict__ x,
        const float* __restrict__ lg, const float* __restrict__ lb,
        __hip_bfloat16* __restrict__ xfb, int last) {
    __shared__ float os[16][65];
    __shared__ float xs[16][65];
    __shared__ float as[16][257];
    int t = threadIdx.x;
    int r0 = blockIdx.x * 16;
    for (int i = t; i < 16 * 64; i += 256)
        os[i >> 6][i & 63] = o[r0 * 64 + i];
    __syncthreads();
    int c = t & 63, rg = t >> 6;
    {
        float pr[4] = {0.f, 0.f, 0.f, 0.f};
        for (int kk = 0; kk < 64; kk++) {
            float w = Wo[kk * 64 + c];
            #pragma unroll
            for (int i = 0; i < 4; i++) pr[i] += os[rg * 4 + i][kk] * w;
        }
        float bias = bo[c];
        #pragma unroll
        for (int i = 0; i < 4; i++) {
            int row = rg * 4 + i;
            xs[row][c] = x[(r0 + row) * 64 + c] + pr[i] + bias;
        }
    }
    __syncthreads();
    {
        int row = t >> 4, sub = t & 15;
        float s = 0.f, s2 = 0.f;
        #pragma unroll
        for (int j = 0; j < 4; j++) { float vv = xs[row][sub * 4 + j]; s += vv; s2 += vv * vv; }
        #pragma unroll
        for (int off = 1; off < 16; off <<= 1) { s += __shfl_xor(s, off); s2 += __shfl_xor(s2, off); }
        float mu = s * (1.f / 64.f);
        float var = s2 * (1.f / 64.f) - mu * mu;
        float rs = rsqrtf(var + EPS);
        #pragma unroll
        for (int j = 0; j < 4; j++) {
            int d = sub * 4 + j;
            os[row][d] = (xs[row][d] - mu) * rs * g2[d] + bg2[d];
        }
    }
    __syncthreads();
    {
        float m1[16];
        #pragma unroll
        for (int i = 0; i < 16; i++) m1[i] = 0.f;
        for (int kk = 0; kk < 64; kk++) {
            float w = W1[kk * NF + t];
            #pragma unroll
            for (int i = 0; i < 16; i++) m1[i] += os[i][kk] * w;
        }
        float bb1 = b1[t];
        #pragma unroll
        for (int i = 0; i < 16; i++) as[i][t] = fmaxf(m1[i] + bb1, 0.f);
    }
    __syncthreads();
    {
        float m2[4] = {0.f, 0.f, 0.f, 0.f};
        for (int kk = 0; kk < 256; kk++) {
            float w = W2[kk * 64 + c];
            #pragma unroll
            for (int i = 0; i < 4; i++) m2[i] += as[rg * 4 + i][kk] * w;
        }
        float bias = b2m[c];
        if (!last) {
            #pragma unroll
            for (int i = 0; i < 4; i++) {
                int row = rg * 4 + i;
                x[(r0 + row) * 64 + c] = xs[row][c] + m2[i] + bias;
            }
        } else {
            #pragma unroll
            for (int i = 0; i < 4; i++) {
                int row = rg * 4 + i;
                os[row][c] = xs[row][c] + m2[i] + bias;
            }
            __syncthreads();
            int row = t >> 4, sub = t & 15;
            float s = 0.f, s2 = 0.f;
            #pragma unroll
            for (int j = 0; j < 4; j++) { float vv = os[row][sub * 4 + j]; s += vv; s2 += vv * vv; }
            #pragma unroll
            for (int off = 1; off < 16; off <<= 1) { s += __shfl_xor(s, off); s2 += __shfl_xor(s2, off); }
            float mu = s * (1.f / 64.f);
            float var = s2 * (1.f / 64.f) - mu * mu;
            float rs = rsqrtf(var + EPS);
            #pragma unroll
            for (int j = 0; j < 4; j++) {
                int d = sub * 4 + j;
                float val = (os[row][d] - mu) * rs * lg[d] + lb[d];
                xfb[(r0 + row) * 64 + d] = __float2bfloat16(val);
            }
        }
    }
}

// ---------------- Whead [64][NV] f32 -> transposed bf16 [NVP][64] ----------------
__global__ __launch_bounds__(256) void k_convW(
        const float* __restrict__ Wh, __hip_bfloat16* __restrict__ whb) {
    __shared__ float w[64][65];
    int t = threadIdx.x;
    int n0 = blockIdx.x * 64;
    for (int i = t; i < 64 * 64; i += 256) {
        int k = i >> 6, c = i & 63;
        int n = n0 + c;
        w[k][c] = (n < NV) ? Wh[k * NV + n] : 0.f;
    }
    __syncthreads();
    int c = t >> 2, kq = t & 3;
    int n = n0 + c;
    union { __hip_bfloat16 h[16]; uint4 u[2]; } pk;
    #pragma unroll
    for (int j = 0; j < 16; j++)
        pk.h[j] = __float2bfloat16(w[kq * 16 + j][c]);
    uint4* dst = (uint4*)(whb + (size_t)n * 64 + kq * 16);
    dst[0] = pk.u[0];
    dst[1] = pk.u[1];
}

// ---------------- head GEMM (bf16 MFMA) + bias + fused row sum-exp ----------------
// grid (NCB2, NN/64); block 256 = 4 waves; wave w: cols cw..cw+63, rows r0..r0+63.
// B-fragment n reads column cw + lr*4 + n  => lane's 4 outputs are consecutive
// columns => one float4 store per row-chunk; bias is one float4 load.
// No max-subtraction: logits ~ N(0,0.16^2), raw sum-exp is safe in f32.
__global__ __launch_bounds__(256) void k_head(
        const __hip_bfloat16* __restrict__ xfb, const __hip_bfloat16* __restrict__ whb,
        const float* __restrict__ bhead, float* __restrict__ out,
        float* __restrict__ wsum) {
    __shared__ float ssm[4][64];

    int t = threadIdx.x;
    int w = t >> 6, l = t & 63;
    int lr = l & 15, lg = l >> 4;
    int cb = blockIdx.x, rb = blockIdx.y;
    int r0 = rb * 64;
    int cw = cb * 256 + w * 64;
    int c4 = cw + lr * 4;                 // this lane's first output column

    bf16x8 a[4][2], b[4][2];
    {
        const __hip_bfloat16* ap = xfb + (size_t)(r0 + lr) * 64 + lg * 8;
        #pragma unroll
        for (int m = 0; m < 4; m++)
            #pragma unroll
            for (int ks = 0; ks < 2; ks++)
                a[m][ks] = *reinterpret_cast<const bf16x8*>(ap + m * 16 * 64 + ks * 32);
        const __hip_bfloat16* bp = whb + (size_t)c4 * 64 + lg * 8;
        #pragma unroll
        for (int n = 0; n < 4; n++)
            #pragma unroll
            for (int ks = 0; ks < 2; ks++)
                b[n][ks] = *reinterpret_cast<const bf16x8*>(bp + n * 64 + ks * 32);
    }

    f32x4 acc[4][4];
    #pragma unroll
    for (int m = 0; m < 4; m++)
        #pragma unroll
        for (int n = 0; n < 4; n++)
            #pragma unroll
            for (int j = 0; j < 4; j++) acc[m][n][j] = 0.f;

    #pragma unroll
    for (int ks = 0; ks < 2; ks++)
        #pragma unroll
        for (int m = 0; m < 4; m++)
            #pragma unroll
            for (int n = 0; n < 4; n++)
                acc[m][n] = __builtin_amdgcn_mfma_f32_16x16x32_bf16(a[m][ks], b[n][ks], acc[m][n], 0, 0, 0);

    bool all4 = (c4 + 3 < NV);
    float bias[4];
    bool  cok[4];
    if (all4) {
        float4 bv = *(const float4*)(bhead + c4);
        bias[0] = bv.x; bias[1] = bv.y; bias[2] = bv.z; bias[3] = bv.w;
        cok[0] = cok[1] = cok[2] = cok[3] = true;
    } else {
        #pragma unroll
        for (int n = 0; n < 4; n++) {
            int gc = c4 + n;
            cok[n] = (gc < NV);
            bias[n] = cok[n] ? bhead[gc] : 0.f;
        }
    }

    #pragma unroll
    for (int m = 0; m < 4; m++) {
        #pragma unroll
        for (int i = 0; i < 4; i++) {
            int rl = 4 * lg + i;
            int grow = r0 + m * 16 + rl;
            float vals[4];
            float es = 0.f;
            #pragma unroll
            for (int n = 0; n < 4; n++) {
                float v = acc[m][n][i] + bias[n];
                vals[n] = v;
                if (cok[n]) es += __expf(v);
            }
            #pragma unroll
            for (int off = 1; off < 16; off <<= 1) es += __shfl_xor(es, off);
            if (lr == 0) ssm[w][m * 16 + rl] = es;
            float* dst = out + (size_t)grow * NV + c4;
            if (all4) {
                float4 vv = make_float4(vals[0], vals[1], vals[2], vals[3]);
                *(float4*)dst = vv;
            } else {
                #pragma unroll
                for (int n = 0; n < 4; n++)
                    if (cok[n]) dst[n] = vals[n];
            }
        }
    }

    __syncthreads();
    if (t < 64)
        wsum[cb * NN + r0 + t] = ssm[0][t] + ssm[1][t] + ssm[2][t] + ssm[3][t];
}

// ---------------- loss stage 1: per-row log(sum-exp) + target logit ----------------
__global__ void k_loss1(const float* __restrict__ wsum,
                        const float* __restrict__ out, const int* __restrict__ targets,
                        float* __restrict__ lp) {
    int row = blockIdx.x * blockDim.x + threadIdx.x;
    if (row >= NN) return;
    float S = 0.f;
    for (int cb = 0; cb < NCB2; cb++)
        S += wsum[cb * NN + row];
    float lse = logf(S);
    int tg = targets[row];
    float lt = out[(size_t)row * NV + tg];
    lp[row] = lt - lse;
}

// ---------------- loss stage 2: deterministic mean ----------------
__global__ void k_loss2(const float* __restrict__ lp, float* __restrict__ out) {
    __shared__ float red[4];
    int t = threadIdx.x;
    float s = 0.f;
    for (int i = t; i < NN; i += 256) s += lp[i];
    for (int off = 1; off < 64; off <<= 1) s += __shfl_xor(s, off);
    if ((t & 63) == 0) red[t >> 6] = s;
    __syncthreads();
    if (t == 0) {
        float tot = red[0] + red[1] + red[2] + red[3];
        out[LOGITS] = -tot / (float)NN;
    }
}

extern "C" void kernel_launch(void* const* d_in, const int* in_sizes, int n_in,
                              void* d_out, int out_size, void* d_ws, size_t ws_size,
                              hipStream_t stream) {
    const int*   idx     = (const int*)d_in[0];
    const int*   targets = (const int*)d_in[1];
    const float* tok     = (const float*)d_in[2];
    const float* pos     = (const float*)d_in[3];
    const float* Wq      = (const float*)d_in[4];
    const float* Wk      = (const float*)d_in[5];
    const float* Wv      = (const float*)d_in[6];
    const float* Wo      = (const float*)d_in[7];
    const float* bo      = (const float*)d_in[8];
    const float* ln1g    = (const float*)d_in[9];
    const float* ln1b    = (const float*)d_in[10];
    const float* ln2g    = (const float*)d_in[11];
    const float* ln2b    = (const float*)d_in[12];
    const float* W1      = (const float*)d_in[13];
    const float* b1      = (const float*)d_in[14];
    const float* W2      = (const float*)d_in[15];
    const float* b2      = (const float*)d_in[16];
    const float* lnfg    = (const float*)d_in[17];
    const float* lnfb    = (const float*)d_in[18];
    const float* Wh      = (const float*)d_in[19];
    const float* bhead   = (const float*)d_in[20];

    float* ws = (float*)d_ws;
    float* x  = ws + X_OFF;
    float* q  = ws + Q_OFF;
    float* k  = ws + K_OFF;
    float* v  = ws + V_OFF;
    float* o  = ws + O_OFF;
    __hip_bfloat16* xfb = (__hip_bfloat16*)(ws + XFB_OFF);
    float* wsm = ws + WS2_OFF;
    __hip_bfloat16* whb = (__hip_bfloat16*)(ws + WHB_OFF);
    float* lp  = ws + LP_OFF;
    float* out = (float*)d_out;

    k_convW<<<NVP / 64, 256, 0, stream>>>(Wh, whb);

    for (int l = 0; l < NL; l++) {
        k_ln_qkv<<<NN / 16, 256, 0, stream>>>(x, ln1g + l * ND, ln1b + l * ND,
                                              Wq + l * NH * ND * NHS, Wk + l * NH * ND * NHS,
                                              Wv + l * NH * ND * NHS, q, k, v,
                                              idx, tok, pos, (l == 0) ? 1 : 0);
        k_attn<<<NB * NH * 4, 256, 0, stream>>>(q, k, v, o);
        k_post<<<NN / 16, 256, 0, stream>>>(o, Wo + l * ND * ND, bo + l * ND,
                                            ln2g + l * ND, ln2b + l * ND,
                                            W1 + l * ND * NF, b1 + l * NF,
                                            W2 + l * NF * ND, b2 + l * ND, x,
                                            lnfg, lnfb, xfb, (l == NL - 1) ? 1 : 0);
    }

    dim3 hgrid(NCB2, NN / 64);
    k_head<<<hgrid, 256, 0, stream>>>(xfb, whb, bhead, out, wsm);

    k_loss1<<<NN / 256, 256, 0, stream>>>(wsm, out, targets, lp);
    k_loss2<<<1, 256, 0, stream>>>(lp, out);
}

// Round 6
// 525.184 us; speedup vs baseline: 3.0211x; 1.1215x over previous
//
#include <hip/hip_runtime.h>
#include <hip/hip_bf16.h>
#include <math.h>

// GPT forward: V=50257, B=16, T=256, D=64, H=4, HS=16, L=4, F=256
constexpr int NV  = 50257;
constexpr int NB  = 16;
constexpr int NT  = 256;
constexpr int ND  = 64;
constexpr int NH  = 4;
constexpr int NHS = 16;
constexpr int NL  = 4;
constexpr int NF  = 256;
constexpr int NN  = NB * NT;        // 4096 rows
constexpr float EPS = 1e-5f;

constexpr int NCB2 = 200;                    // head col blocks of 256 (8-divisible for XCD chunking)
constexpr int NVP  = NCB2 * 256;             // 51200 padded vocab
constexpr int LOGITS = NN * NV;              // 205,852,672
constexpr int RB_N  = NN / 64;               // 64 row blocks
constexpr int CB_PER_XCD = NCB2 / 8;         // 25

// workspace layout (float offsets)
constexpr int X_OFF   = 0;                        // [NN*ND]
constexpr int Q_OFF   = X_OFF  + NN * ND;
constexpr int K_OFF   = Q_OFF  + NN * ND;
constexpr int V_OFF   = K_OFF  + NN * ND;
constexpr int O_OFF   = V_OFF  + NN * ND;
constexpr int A_OFF   = O_OFF  + NN * ND;         // (spacer)
constexpr int XFB_OFF = A_OFF  + NN * NF;         // bf16 [NN*ND] -> NN*ND/2 floats
constexpr int WM_OFF  = XFB_OFF + NN * ND / 2;    // (spacer)
constexpr int WS2_OFF = WM_OFF + NCB2 * NN;       // [NCB2*NN] sum-exp partials
constexpr int WHB_OFF = WS2_OFF + NCB2 * NN;      // bf16 [NVP*64] -> NVP*32 floats
constexpr int LP_OFF  = WHB_OFF + NVP * 32;       // [NN]

typedef __bf16 bf16x8 __attribute__((ext_vector_type(8)));
typedef float  f32x4  __attribute__((ext_vector_type(4)));

// ---------------- LN1 + QKV  (16 rows/block, 256 blocks); first: fused embed ----------------
__global__ __launch_bounds__(256) void k_ln_qkv(
        float* __restrict__ x, const float* __restrict__ g, const float* __restrict__ bb,
        const float* __restrict__ Wq, const float* __restrict__ Wk, const float* __restrict__ Wv,
        float* __restrict__ q, float* __restrict__ k, float* __restrict__ v,
        const int* __restrict__ idx, const float* __restrict__ tok,
        const float* __restrict__ pos, int first) {
    __shared__ float hs[16][65];
    int t = threadIdx.x;
    int r0 = blockIdx.x * 16;
    if (first) {
        for (int i = t; i < 16 * 64; i += 256) {
            int n = r0 + (i >> 6);
            int tt = n & (NT - 1), d = i & 63;
            float e = tok[idx[n] * ND + d] + pos[tt * ND + d];
            hs[i >> 6][i & 63] = e;
            x[(size_t)r0 * 64 + i] = e;
        }
    } else {
        for (int i = t; i < 16 * 64; i += 256)
            hs[i >> 6][i & 63] = x[r0 * 64 + i];
    }
    __syncthreads();
    {
        int row = t >> 4, sub = t & 15;
        float s = 0.f, s2 = 0.f;
        #pragma unroll
        for (int j = 0; j < 4; j++) { float vv = hs[row][sub * 4 + j]; s += vv; s2 += vv * vv; }
        #pragma unroll
        for (int off = 1; off < 16; off <<= 1) { s += __shfl_xor(s, off); s2 += __shfl_xor(s2, off); }
        float mu = s * (1.f / 64.f);
        float var = s2 * (1.f / 64.f) - mu * mu;
        float rs = rsqrtf(var + EPS);
        #pragma unroll
        for (int j = 0; j < 4; j++) {
            int d = sub * 4 + j;
            hs[row][d] = (hs[row][d] - mu) * rs * g[d] + bb[d];
        }
    }
    __syncthreads();
    int c = t & 63, rg = t >> 6;
    int head = c >> 4, sidx = c & 15;
    float aq[4], ak[4], av[4];
    #pragma unroll
    for (int i = 0; i < 4; i++) { aq[i] = 0.f; ak[i] = 0.f; av[i] = 0.f; }
    for (int kk = 0; kk < 64; kk++) {
        float wq = Wq[(head * 64 + kk) * 16 + sidx];
        float wk = Wk[(head * 64 + kk) * 16 + sidx];
        float wv = Wv[(head * 64 + kk) * 16 + sidx];
        #pragma unroll
        for (int i = 0; i < 4; i++) {
            float h = hs[rg * 4 + i][kk];
            aq[i] += h * wq; ak[i] += h * wk; av[i] += h * wv;
        }
    }
    #pragma unroll
    for (int i = 0; i < 4; i++) {
        int n = r0 + rg * 4 + i;
        int b = n >> 8, tt = n & 255;
        int oidx = ((b * NH + head) * NT + tt) * NHS + sidx;
        q[oidx] = aq[i]; k[oidx] = ak[i]; v[oidx] = av[i];
    }
}

// ---------------- fused causal attention (split-u), 256 blocks ----------------
__global__ __launch_bounds__(256) void k_attn(
        const float* __restrict__ q, const float* __restrict__ k,
        const float* __restrict__ v, float* __restrict__ o) {
    __shared__ float ks[256][16];
    __shared__ float vs[256][16];
    int blk = blockIdx.x;
    int bh = blk >> 2;
    int tq = blk & 3;
    int t = threadIdx.x;
    int tl = t >> 2, sub = t & 3;
    int tt = tq * 64 + tl;
    int nrows = tq * 64 + 64;
    const float* kb = k + bh * NT * NHS;
    const float* vb = v + bh * NT * NHS;
    for (int i = t; i < nrows * 16; i += 256) {
        (&ks[0][0])[i] = kb[i];
        (&vs[0][0])[i] = vb[i];
    }
    __syncthreads();
    float qr[16];
    const float* qp = q + bh * NT * NHS + tt * NHS;
    #pragma unroll
    for (int j = 0; j < 16; j += 4) {
        float4 qv = *(const float4*)(qp + j);
        qr[j] = qv.x; qr[j+1] = qv.y; qr[j+2] = qv.z; qr[j+3] = qv.w;
    }
    float m = -1e30f, l = 0.f, acc[16];
    #pragma unroll
    for (int j = 0; j < 16; j++) acc[j] = 0.f;
    for (int u = sub; u <= tt; u += 4) {
        float s = 0.f;
        #pragma unroll
        for (int j = 0; j < 16; j++) s += qr[j] * ks[u][j];
        float mn = fmaxf(m, s);
        float corr = __expf(m - mn);
        float p = __expf(s - mn);
        l = l * corr + p;
        #pragma unroll
        for (int j = 0; j < 16; j++) acc[j] = acc[j] * corr + p * vs[u][j];
        m = mn;
    }
    #pragma unroll
    for (int off = 1; off < 4; off <<= 1) {
        float mo = __shfl_xor(m, off);
        float lo = __shfl_xor(l, off);
        float mn = fmaxf(m, mo);
        float c1 = __expf(m - mn), c2 = __expf(mo - mn);
        l = l * c1 + lo * c2;
        #pragma unroll
        for (int j = 0; j < 16; j++) {
            float ao = __shfl_xor(acc[j], off);
            acc[j] = acc[j] * c1 + ao * c2;
        }
        m = mn;
    }
    float inv = 1.f / l;
    int b = bh >> 2, h = bh & 3;
    float* op = o + (b * NT + tt) * ND + h * NHS;
    float o0, o1, o2, o3;
    if (sub == 0)      { o0 = acc[0];  o1 = acc[1];  o2 = acc[2];  o3 = acc[3];  }
    else if (sub == 1) { o0 = acc[4];  o1 = acc[5];  o2 = acc[6];  o3 = acc[7];  }
    else if (sub == 2) { o0 = acc[8];  o1 = acc[9];  o2 = acc[10]; o3 = acc[11]; }
    else               { o0 = acc[12]; o1 = acc[13]; o2 = acc[14]; o3 = acc[15]; }
    float4 ov = make_float4(o0 * inv, o1 * inv, o2 * inv, o3 * inv);
    *(float4*)(op + sub * 4) = ov;
}

// ---------------- fused proj+res+LN2+MLP1+MLP2+res (16 rows/block) ----------------
__global__ __launch_bounds__(256) void k_post(
        const float* __restrict__ o, const float* __restrict__ Wo, const float* __restrict__ bo,
        const float* __restrict__ g2, const float* __restrict__ bg2,
        const float* __restrict__ W1, const float* __restrict__ b1,
        const float* __restrict__ W2, const float* __restrict__ b2m,
        float* __restrict__ x,
        const float* __restrict__ lg, const float* __restrict__ lb,
        __hip_bfloat16* __restrict__ xfb, int last) {
    __shared__ float os[16][65];
    __shared__ float xs[16][65];
    __shared__ float as[16][257];
    int t = threadIdx.x;
    int r0 = blockIdx.x * 16;
    for (int i = t; i < 16 * 64; i += 256)
        os[i >> 6][i & 63] = o[r0 * 64 + i];
    __syncthreads();
    int c = t & 63, rg = t >> 6;
    {
        float pr[4] = {0.f, 0.f, 0.f, 0.f};
        for (int kk = 0; kk < 64; kk++) {
            float w = Wo[kk * 64 + c];
            #pragma unroll
            for (int i = 0; i < 4; i++) pr[i] += os[rg * 4 + i][kk] * w;
        }
        float bias = bo[c];
        #pragma unroll
        for (int i = 0; i < 4; i++) {
            int row = rg * 4 + i;
            xs[row][c] = x[(r0 + row) * 64 + c] + pr[i] + bias;
        }
    }
    __syncthreads();
    {
        int row = t >> 4, sub = t & 15;
        float s = 0.f, s2 = 0.f;
        #pragma unroll
        for (int j = 0; j < 4; j++) { float vv = xs[row][sub * 4 + j]; s += vv; s2 += vv * vv; }
        #pragma unroll
        for (int off = 1; off < 16; off <<= 1) { s += __shfl_xor(s, off); s2 += __shfl_xor(s2, off); }
        float mu = s * (1.f / 64.f);
        float var = s2 * (1.f / 64.f) - mu * mu;
        float rs = rsqrtf(var + EPS);
        #pragma unroll
        for (int j = 0; j < 4; j++) {
            int d = sub * 4 + j;
            os[row][d] = (xs[row][d] - mu) * rs * g2[d] + bg2[d];
        }
    }
    __syncthreads();
    {
        float m1[16];
        #pragma unroll
        for (int i = 0; i < 16; i++) m1[i] = 0.f;
        for (int kk = 0; kk < 64; kk++) {
            float w = W1[kk * NF + t];
            #pragma unroll
            for (int i = 0; i < 16; i++) m1[i] += os[i][kk] * w;
        }
        float bb1 = b1[t];
        #pragma unroll
        for (int i = 0; i < 16; i++) as[i][t] = fmaxf(m1[i] + bb1, 0.f);
    }
    __syncthreads();
    {
        float m2[4] = {0.f, 0.f, 0.f, 0.f};
        for (int kk = 0; kk < 256; kk++) {
            float w = W2[kk * 64 + c];
            #pragma unroll
            for (int i = 0; i < 4; i++) m2[i] += as[rg * 4 + i][kk] * w;
        }
        float bias = b2m[c];
        if (!last) {
            #pragma unroll
            for (int i = 0; i < 4; i++) {
                int row = rg * 4 + i;
                x[(r0 + row) * 64 + c] = xs[row][c] + m2[i] + bias;
            }
        } else {
            #pragma unroll
            for (int i = 0; i < 4; i++) {
                int row = rg * 4 + i;
                os[row][c] = xs[row][c] + m2[i] + bias;
            }
            __syncthreads();
            int row = t >> 4, sub = t & 15;
            float s = 0.f, s2 = 0.f;
            #pragma unroll
            for (int j = 0; j < 4; j++) { float vv = os[row][sub * 4 + j]; s += vv; s2 += vv * vv; }
            #pragma unroll
            for (int off = 1; off < 16; off <<= 1) { s += __shfl_xor(s, off); s2 += __shfl_xor(s2, off); }
            float mu = s * (1.f / 64.f);
            float var = s2 * (1.f / 64.f) - mu * mu;
            float rs = rsqrtf(var + EPS);
            #pragma unroll
            for (int j = 0; j < 4; j++) {
                int d = sub * 4 + j;
                float val = (os[row][d] - mu) * rs * lg[d] + lb[d];
                xfb[(r0 + row) * 64 + d] = __float2bfloat16(val);
            }
        }
    }
}

// ---------------- Whead [64][NV] f32 -> transposed bf16 [NVP][64] ----------------
__global__ __launch_bounds__(256) void k_convW(
        const float* __restrict__ Wh, __hip_bfloat16* __restrict__ whb) {
    __shared__ float w[64][65];
    int t = threadIdx.x;
    int n0 = blockIdx.x * 64;
    for (int i = t; i < 64 * 64; i += 256) {
        int k = i >> 6, c = i & 63;
        int n = n0 + c;
        w[k][c] = (n < NV) ? Wh[k * NV + n] : 0.f;
    }
    __syncthreads();
    int c = t >> 2, kq = t & 3;
    int n = n0 + c;
    union { __hip_bfloat16 h[16]; uint4 u[2]; } pk;
    #pragma unroll
    for (int j = 0; j < 16; j++)
        pk.h[j] = __float2bfloat16(w[kq * 16 + j][c]);
    uint4* dst = (uint4*)(whb + (size_t)n * 64 + kq * 16);
    dst[0] = pk.u[0];
    dst[1] = pk.u[1];
}

// ---------------- head GEMM (bf16 MFMA) + bias + fused row sum-exp ----------------
// 1D grid of NCB2*RB_N blocks, XCD-chunked: block i -> XCD x=i&7 handles a
// CONTIGUOUS 25-wide cb chunk per row-panel, so each XCD's L2 write-evictions
// form near-sequential HBM streams (DRAM page locality).
__global__ __launch_bounds__(256) void k_head(
        const __hip_bfloat16* __restrict__ xfb, const __hip_bfloat16* __restrict__ whb,
        const float* __restrict__ bhead, float* __restrict__ out,
        float* __restrict__ wsum) {
    __shared__ float ssm[4][64];

    int i0 = blockIdx.x;
    int xcd = i0 & 7;
    int j  = i0 >> 3;               // 0..1599
    int rb = j / CB_PER_XCD;        // 0..63
    int cb = xcd * CB_PER_XCD + (j - rb * CB_PER_XCD);   // 0..199

    int t = threadIdx.x;
    int w = t >> 6, l = t & 63;
    int lr = l & 15, lg = l >> 4;
    int r0 = rb * 64;
    int cw = cb * 256 + w * 64;
    int c4 = cw + lr * 4;                 // this lane's first output column

    bf16x8 a[4][2], b[4][2];
    {
        const __hip_bfloat16* ap = xfb + (size_t)(r0 + lr) * 64 + lg * 8;
        #pragma unroll
        for (int m = 0; m < 4; m++)
            #pragma unroll
            for (int ks = 0; ks < 2; ks++)
                a[m][ks] = *reinterpret_cast<const bf16x8*>(ap + m * 16 * 64 + ks * 32);
        const __hip_bfloat16* bp = whb + (size_t)c4 * 64 + lg * 8;
        #pragma unroll
        for (int n = 0; n < 4; n++)
            #pragma unroll
            for (int ks = 0; ks < 2; ks++)
                b[n][ks] = *reinterpret_cast<const bf16x8*>(bp + n * 64 + ks * 32);
    }

    f32x4 acc[4][4];
    #pragma unroll
    for (int m = 0; m < 4; m++)
        #pragma unroll
        for (int n = 0; n < 4; n++)
            #pragma unroll
            for (int j2 = 0; j2 < 4; j2++) acc[m][n][j2] = 0.f;

    #pragma unroll
    for (int ks = 0; ks < 2; ks++)
        #pragma unroll
        for (int m = 0; m < 4; m++)
            #pragma unroll
            for (int n = 0; n < 4; n++)
                acc[m][n] = __builtin_amdgcn_mfma_f32_16x16x32_bf16(a[m][ks], b[n][ks], acc[m][n], 0, 0, 0);

    bool all4 = (c4 + 3 < NV);
    float bias[4];
    bool  cok[4];
    if (all4) {
        float4 bv = *(const float4*)(bhead + c4);
        bias[0] = bv.x; bias[1] = bv.y; bias[2] = bv.z; bias[3] = bv.w;
        cok[0] = cok[1] = cok[2] = cok[3] = true;
    } else {
        #pragma unroll
        for (int n = 0; n < 4; n++) {
            int gc = c4 + n;
            cok[n] = (gc < NV);
            bias[n] = cok[n] ? bhead[gc] : 0.f;
        }
    }

    #pragma unroll
    for (int m = 0; m < 4; m++) {
        #pragma unroll
        for (int i = 0; i < 4; i++) {
            int rl = 4 * lg + i;
            int grow = r0 + m * 16 + rl;
            float vals[4];
            float es = 0.f;
            #pragma unroll
            for (int n = 0; n < 4; n++) {
                float v = acc[m][n][i] + bias[n];
                vals[n] = v;
                if (cok[n]) es += __expf(v);
            }
            #pragma unroll
            for (int off = 1; off < 16; off <<= 1) es += __shfl_xor(es, off);
            if (lr == 0) ssm[w][m * 16 + rl] = es;
            float* dst = out + (size_t)grow * NV + c4;
            if (all4) {
                float4 vv = make_float4(vals[0], vals[1], vals[2], vals[3]);
                *(float4*)dst = vv;
            } else {
                #pragma unroll
                for (int n = 0; n < 4; n++)
                    if (cok[n]) dst[n] = vals[n];
            }
        }
    }

    __syncthreads();
    if (t < 64)
        wsum[cb * NN + r0 + t] = ssm[0][t] + ssm[1][t] + ssm[2][t] + ssm[3][t];
}

// ---------------- loss stage 1: per-row log(sum-exp) + target logit ----------------
__global__ void k_loss1(const float* __restrict__ wsum,
                        const float* __restrict__ out, const int* __restrict__ targets,
                        float* __restrict__ lp) {
    int row = blockIdx.x * blockDim.x + threadIdx.x;
    if (row >= NN) return;
    float S = 0.f;
    for (int cb = 0; cb < NCB2; cb++)
        S += wsum[cb * NN + row];
    float lse = logf(S);
    int tg = targets[row];
    float lt = out[(size_t)row * NV + tg];
    lp[row] = lt - lse;
}

// ---------------- loss stage 2: deterministic mean ----------------
__global__ void k_loss2(const float* __restrict__ lp, float* __restrict__ out) {
    __shared__ float red[4];
    int t = threadIdx.x;
    float s = 0.f;
    for (int i = t; i < NN; i += 256) s += lp[i];
    for (int off = 1; off < 64; off <<= 1) s += __shfl_xor(s, off);
    if ((t & 63) == 0) red[t >> 6] = s;
    __syncthreads();
    if (t == 0) {
        float tot = red[0] + red[1] + red[2] + red[3];
        out[LOGITS] = -tot / (float)NN;
    }
}

extern "C" void kernel_launch(void* const* d_in, const int* in_sizes, int n_in,
                              void* d_out, int out_size, void* d_ws, size_t ws_size,
                              hipStream_t stream) {
    const int*   idx     = (const int*)d_in[0];
    const int*   targets = (const int*)d_in[1];
    const float* tok     = (const float*)d_in[2];
    const float* pos     = (const float*)d_in[3];
    const float* Wq      = (const float*)d_in[4];
    const float* Wk      = (const float*)d_in[5];
    const float* Wv      = (const float*)d_in[6];
    const float* Wo      = (const float*)d_in[7];
    const float* bo      = (const float*)d_in[8];
    const float* ln1g    = (const float*)d_in[9];
    const float* ln1b    = (const float*)d_in[10];
    const float* ln2g    = (const float*)d_in[11];
    const float* ln2b    = (const float*)d_in[12];
    const float* W1      = (const float*)d_in[13];
    const float* b1      = (const float*)d_in[14];
    const float* W2      = (const float*)d_in[15];
    const float* b2      = (const float*)d_in[16];
    const float* lnfg    = (const float*)d_in[17];
    const float* lnfb    = (const float*)d_in[18];
    const float* Wh      = (const float*)d_in[19];
    const float* bhead   = (const float*)d_in[20];

    float* ws = (float*)d_ws;
    float* x  = ws + X_OFF;
    float* q  = ws + Q_OFF;
    float* k  = ws + K_OFF;
    float* v  = ws + V_OFF;
    float* o  = ws + O_OFF;
    __hip_bfloat16* xfb = (__hip_bfloat16*)(ws + XFB_OFF);
    float* wsm = ws + WS2_OFF;
    __hip_bfloat16* whb = (__hip_bfloat16*)(ws + WHB_OFF);
    float* lp  = ws + LP_OFF;
    float* out = (float*)d_out;

    k_convW<<<NVP / 64, 256, 0, stream>>>(Wh, whb);

    for (int l = 0; l < NL; l++) {
        k_ln_qkv<<<NN / 16, 256, 0, stream>>>(x, ln1g + l * ND, ln1b + l * ND,
                                              Wq + l * NH * ND * NHS, Wk + l * NH * ND * NHS,
                                              Wv + l * NH * ND * NHS, q, k, v,
                                              idx, tok, pos, (l == 0) ? 1 : 0);
        k_attn<<<NB * NH * 4, 256, 0, stream>>>(q, k, v, o);
        k_post<<<NN / 16, 256, 0, stream>>>(o, Wo + l * ND * ND, bo + l * ND,
                                            ln2g + l * ND, ln2b + l * ND,
                                            W1 + l * ND * NF, b1 + l * NF,
                                            W2 + l * NF * ND, b2 + l * ND, x,
                                            lnfg, lnfb, xfb, (l == NL - 1) ? 1 : 0);
    }

    k_head<<<NCB2 * RB_N, 256, 0, stream>>>(xfb, whb, bhead, out, wsm);

    k_loss1<<<NN / 256, 256, 0, stream>>>(wsm, out, targets, lp);
    k_loss2<<<1, 256, 0, stream>>>(lp, out);
}